// Round 5
// baseline (2503.393 us; speedup 1.0000x reference)
//
#include <hip/hip_runtime.h>
#include <hip/hip_bf16.h>
#include <math.h>

#define NN 100000
#define EE 1600000
#define INC 512
#define HIDC 100

// ---------- bf16 helpers (avoid header struct details) ----------
static __device__ __forceinline__ unsigned short f2bf(float f) {
  unsigned u = __float_as_uint(f);
  return (unsigned short)((u + (0x7fffu + ((u >> 16) & 1u))) >> 16);
}
static __device__ __forceinline__ float bf_lo(unsigned v) {
  return __uint_as_float(v << 16);
}
static __device__ __forceinline__ float bf_hi(unsigned v) {
  return __uint_as_float(v & 0xffff0000u);
}

// ---------- 1) histogram of dst ----------
__global__ void k_hist(const int* __restrict__ ei, int* __restrict__ cnt) {
  int e = blockIdx.x * 256 + threadIdx.x;
  if (e < EE) atomicAdd(&cnt[ei[EE + e]], 1);
}

// ---------- 2) single-block exclusive scan + dinv ----------
__global__ __launch_bounds__(1024) void k_scan(const int* __restrict__ cnt,
                                               int* __restrict__ row_start,
                                               int* __restrict__ cursor,
                                               float* __restrict__ dinv) {
  __shared__ int sums[1024];
  int t = threadIdx.x;
  const int CH = (NN + 1023) >> 10;  // 98
  int lo = t * CH;
  int hi = lo + CH; if (hi > NN) hi = NN;
  if (lo > NN) lo = NN;
  int s = 0;
  for (int i = lo; i < hi; i++) s += cnt[i];
  sums[t] = s;
  __syncthreads();
  for (int off = 1; off < 1024; off <<= 1) {
    int v = sums[t];
    int u = (t >= off) ? sums[t - off] : 0;
    __syncthreads();
    sums[t] = v + u;
    __syncthreads();
  }
  int run = (t == 0) ? 0 : sums[t - 1];
  for (int i = lo; i < hi; i++) {
    int c = cnt[i];
    row_start[i] = run;
    cursor[i] = run;
    dinv[i] = rsqrtf((float)(c + 1));  // +1 self-loop
    run += c;
  }
  if (t == 1023) row_start[NN] = run;
}

// ---------- 3) fill CSR (by dst) ----------
__global__ void k_fill(const int* __restrict__ ei, int* __restrict__ cursor,
                       int* __restrict__ csr) {
  int e = blockIdx.x * 256 + threadIdx.x;
  if (e < EE) {
    int d = ei[EE + e];
    int pos = atomicAdd(&cursor[d], 1);
    csr[pos] = ei[e];  // src
  }
}

// ---------- 4) fused GEMM: hp = bf16(dinv*(x@W1)), skip2 = x@Ws + bs ----------
__global__ __launch_bounds__(256) void k_gemm1(const float* __restrict__ x,
                                               const float* __restrict__ W1,
                                               const float* __restrict__ Wsk,
                                               const float* __restrict__ bsk,
                                               const float* __restrict__ dinv,
                                               unsigned* __restrict__ hp32,
                                               float* __restrict__ skip2) {
  __shared__ float xs[256 * 17];     // 256 rows x 16 k, pad 17
  __shared__ float wl[16 * 102];     // [k][c], c<100 -> W1, c>=100 -> Ws
  int t = threadIdx.x;
  int row0 = blockIdx.x * 256;
  float acc[102];
#pragma unroll
  for (int c = 0; c < 102; c++) acc[c] = 0.f;

  for (int k0 = 0; k0 < INC; k0 += 16) {
    __syncthreads();  // protect previous-iteration reads
#pragma unroll
    for (int i = 0; i < 16; i++) {
      int flat = i * 256 + t;
      int r = flat >> 4, k = flat & 15;
      int row = row0 + r;
      xs[r * 17 + k] = (row < NN) ? x[row * INC + k0 + k] : 0.f;
    }
    for (int idx = t; idx < 16 * 102; idx += 256) {
      int k = idx / 102, c = idx - k * 102;
      wl[idx] = (c < 100) ? W1[(k0 + k) * 100 + c] : Wsk[(k0 + k) * 2 + (c - 100)];
    }
    __syncthreads();
#pragma unroll
    for (int k = 0; k < 16; k++) {
      float xv = xs[t * 17 + k];
#pragma unroll
      for (int c = 0; c < 102; c++)
        acc[c] = fmaf(xv, wl[k * 102 + c], acc[c]);
    }
  }

  int row = row0 + t;
  if (row < NN) {
    float dv = dinv[row];
#pragma unroll
    for (int c = 0; c < 100; c += 2) {
      unsigned pk = ((unsigned)f2bf(dv * acc[c + 1]) << 16) | (unsigned)f2bf(dv * acc[c]);
      hp32[row * 50 + (c >> 1)] = pk;
    }
    skip2[row * 2 + 0] = acc[100] + bsk[0];
    skip2[row * 2 + 1] = acc[101] + bsk[1];
  }
}

// ---------- 5) aggregate conv1: h1 = relu(dinv*(sum hp[src] + hp[i]) + b1) ----------
__global__ __launch_bounds__(256) void k_agg1(const unsigned* __restrict__ hp32,
                                              const int* __restrict__ csr,
                                              const int* __restrict__ row_start,
                                              const int* __restrict__ cnt,
                                              const float* __restrict__ dinv,
                                              const float* __restrict__ b1,
                                              float2* __restrict__ h1) {
  int node = blockIdx.x * 4 + (threadIdx.x >> 6);  // one wave per node
  int lane = threadIdx.x & 63;
  bool act = lane < 50;
  int start = row_start[node];
  int len = cnt[node];
  float a0 = 0.f, a1 = 0.f;
  if (act) {
    unsigned v = hp32[node * 50 + lane];  // self-loop term
    a0 = bf_lo(v); a1 = bf_hi(v);
  }
  int s = (len > 0) ? csr[start] : 0;
  for (int j = 0; j < len; j++) {
    int snext = (j + 1 < len) ? csr[start + j + 1] : 0;
    if (act) {
      unsigned v = hp32[s * 50 + lane];
      a0 += bf_lo(v); a1 += bf_hi(v);
    }
    s = snext;
  }
  if (act) {
    float dv = dinv[node];
    float r0 = fmaxf(fmaf(dv, a0, b1[2 * lane]), 0.f);
    float r1 = fmaxf(fmaf(dv, a1, b1[2 * lane + 1]), 0.f);
    h1[node * 50 + lane] = make_float2(r0, r1);
  }
}

// ---------- 6) p = dinv * (h1 @ W2) ----------
__global__ __launch_bounds__(256) void k_gemm2(const float* __restrict__ h1,
                                               const float* __restrict__ W2,
                                               const float* __restrict__ dinv,
                                               float* __restrict__ p) {
  __shared__ float xs[128 * 101];
  __shared__ float w2s[200];
  int t = threadIdx.x;
  int r0 = blockIdx.x * 128;
  if (t < 200) w2s[t] = W2[t];
  for (int idx = t; idx < 128 * 100; idx += 256) {
    int r = idx / 100, f = idx - r * 100;
    int g = r0 + r;
    xs[r * 101 + f] = (g < NN) ? h1[g * 100 + f] : 0.f;
  }
  __syncthreads();
  int r = t >> 1, c = t & 1;
  int g = r0 + r;
  if (g < NN) {
    float acc = 0.f;
#pragma unroll
    for (int f = 0; f < 100; f++)
      acc = fmaf(xs[r * 101 + f], w2s[2 * f + c], acc);
    p[g * 2 + c] = dinv[g] * acc;
  }
}

// ---------- 7) conv2 aggregate + skip + log_softmax ----------
__global__ __launch_bounds__(256) void k_final(const float2* __restrict__ p,
                                               const int* __restrict__ csr,
                                               const int* __restrict__ row_start,
                                               const int* __restrict__ cnt,
                                               const float* __restrict__ dinv,
                                               const float* __restrict__ b2,
                                               const float2* __restrict__ skip2,
                                               float2* __restrict__ out) {
  int i = blockIdx.x * 256 + threadIdx.x;
  if (i >= NN) return;
  float2 pi = p[i];
  float a0 = pi.x, a1 = pi.y;  // self-loop
  int start = row_start[i], len = cnt[i];
  for (int j = 0; j < len; j++) {
    int s = csr[start + j];
    float2 ps = p[s];
    a0 += ps.x; a1 += ps.y;
  }
  float dv = dinv[i];
  float2 sk = skip2[i];
  float v0 = dv * a0 + b2[0] + sk.x;
  float v1 = dv * a1 + b2[1] + sk.y;
  float m = fmaxf(v0, v1);
  float lse = m + logf(expf(v0 - m) + expf(v1 - m));
  out[i] = make_float2(v0 - lse, v1 - lse);
}

extern "C" void kernel_launch(void* const* d_in, const int* in_sizes, int n_in,
                              void* d_out, int out_size, void* d_ws, size_t ws_size,
                              hipStream_t stream) {
  const float* x   = (const float*)d_in[0];
  const int*   ei  = (const int*)d_in[1];
  const float* W1  = (const float*)d_in[2];
  const float* b1  = (const float*)d_in[3];
  const float* W2  = (const float*)d_in[4];
  const float* b2  = (const float*)d_in[5];
  const float* Wsk = (const float*)d_in[6];
  const float* bsk = (const float*)d_in[7];
  float* out = (float*)d_out;

  char* w = (char*)d_ws;
  size_t off = 0;
  auto alloc = [&](size_t bytes) {
    void* ptr = w + off;
    off += (bytes + 255) & ~(size_t)255;
    return ptr;
  };
  int*      cnt   = (int*)alloc((size_t)NN * 4);
  int*      rs    = (int*)alloc((size_t)(NN + 1) * 4);
  int*      cur   = (int*)alloc((size_t)NN * 4);
  float*    dinv  = (float*)alloc((size_t)NN * 4);
  int*      csr   = (int*)alloc((size_t)EE * 4);
  unsigned* hp    = (unsigned*)alloc((size_t)NN * 50 * 4);  // bf16 x2 packed
  float*    skip2 = (float*)alloc((size_t)NN * 2 * 4);
  float*    h1    = (float*)alloc((size_t)NN * 100 * 4);
  float*    p     = (float*)alloc((size_t)NN * 2 * 4);

  hipMemsetAsync(cnt, 0, (size_t)NN * 4, stream);
  k_hist<<<EE / 256, 256, 0, stream>>>(ei, cnt);
  k_scan<<<1, 1024, 0, stream>>>(cnt, rs, cur, dinv);
  k_fill<<<EE / 256, 256, 0, stream>>>(ei, cur, csr);
  k_gemm1<<<(NN + 255) / 256, 256, 0, stream>>>(x, W1, Wsk, bsk, dinv, hp, skip2);
  k_agg1<<<NN / 4, 256, 0, stream>>>(hp, csr, rs, cnt, dinv, b1, (float2*)h1);
  k_gemm2<<<(NN + 127) / 128, 256, 0, stream>>>(h1, W2, dinv, p);
  k_final<<<(NN + 255) / 256, 256, 0, stream>>>((const float2*)p, csr, rs, cnt,
                                                dinv, b2, (const float2*)skip2,
                                                (float2*)out);
}

// Round 10
// 985.090 us; speedup vs baseline: 2.5413x; 2.5413x over previous
//
#include <hip/hip_runtime.h>
#include <hip/hip_bf16.h>
#include <math.h>

#define NN 100000
#define EE 1600000
#define INC 512
#define HIDC 100

typedef __attribute__((ext_vector_type(8))) short bf16x8;
typedef __attribute__((ext_vector_type(4))) float f32x4;

static __device__ __forceinline__ unsigned short f2bf(float f) {
  unsigned u = __float_as_uint(f);
  return (unsigned short)((u + (0x7fffu + ((u >> 16) & 1u))) >> 16);
}
static __device__ __forceinline__ float bf_lo(unsigned v) {
  return __uint_as_float(v << 16);
}
static __device__ __forceinline__ float bf_hi(unsigned v) {
  return __uint_as_float(v & 0xffff0000u);
}

// swizzle for [row][64] bf16 tiles (128 B/row): XOR chunk bits with row&7
#define SWZ(row, byteoff) (((row) * 128 + ((byteoff) ^ (((row) & 7) << 4))))
// swizzle for [row][128] bf16 output tile (256 B/row)
#define SWZ2(row, byteoff) (((row) * 256 + ((byteoff) ^ (((row) & 7) << 4))))

// ---------- 0) W prep: wt[c][k] = bf16(W1[k][c] | Ws[k][c-100] | 0), c<128 ----------
__global__ void k_wprep(const float* __restrict__ W1, const float* __restrict__ Wsk,
                        short* __restrict__ wt) {
  int t = blockIdx.x * 256 + threadIdx.x;  // 65536 total
  int c = t >> 9, k = t & 511;
  float v = 0.f;
  if (c < 100) v = W1[k * 100 + c];
  else if (c < 102) v = Wsk[k * 2 + (c - 100)];
  wt[c * 512 + k] = (short)f2bf(v);
}

// ---------- 1) histogram of dst ----------
__global__ void k_hist(const int* __restrict__ ei, int* __restrict__ cnt) {
  int e = blockIdx.x * 256 + threadIdx.x;
  if (e < EE) atomicAdd(&cnt[ei[EE + e]], 1);
}

// ---------- 2) single-block exclusive scan + dinv ----------
__global__ __launch_bounds__(1024) void k_scan(const int* __restrict__ cnt,
                                               int* __restrict__ row_start,
                                               int* __restrict__ cursor,
                                               float* __restrict__ dinv) {
  __shared__ int sums[1024];
  int t = threadIdx.x;
  const int CH = (NN + 1023) >> 10;  // 98
  int lo = t * CH;
  int hi = lo + CH; if (hi > NN) hi = NN;
  if (lo > NN) lo = NN;
  int s = 0;
  for (int i = lo; i < hi; i++) s += cnt[i];
  sums[t] = s;
  __syncthreads();
  for (int off = 1; off < 1024; off <<= 1) {
    int v = sums[t];
    int u = (t >= off) ? sums[t - off] : 0;
    __syncthreads();
    sums[t] = v + u;
    __syncthreads();
  }
  int run = (t == 0) ? 0 : sums[t - 1];
  for (int i = lo; i < hi; i++) {
    int c = cnt[i];
    row_start[i] = run;
    cursor[i] = run;
    dinv[i] = rsqrtf((float)(c + 1));  // +1 self-loop
    run += c;
  }
  if (t == 1023) row_start[NN] = run;
}

// ---------- 3) fill CSR (by dst) ----------
__global__ void k_fill(const int* __restrict__ ei, int* __restrict__ cursor,
                       int* __restrict__ csr) {
  int e = blockIdx.x * 256 + threadIdx.x;
  if (e < EE) {
    int d = ei[EE + e];
    int pos = atomicAdd(&cursor[d], 1);
    csr[pos] = ei[e];  // src
  }
}

// ---------- 4) MFMA GEMM: hp = bf16(dinv*(x@W1)), skip2 = x@Ws + bs ----------
// tile: 128 rows x 128 cols (cols 0-99 = W1, 100-101 = Ws, 102-127 pad)
// K = 512, BK = 64, double-buffered LDS, bf16 mfma_f32_16x16x32
__global__ __launch_bounds__(256) void k_gemm1m(const float* __restrict__ x,
                                                const short* __restrict__ wt,
                                                const float* __restrict__ bsk,
                                                const float* __restrict__ dinv,
                                                unsigned* __restrict__ hp32,
                                                float* __restrict__ skip2) {
  __shared__ short xsb[2][8192];  // [128 rows][64 k] bf16 swizzled, 16 KB each
  __shared__ short wsb[2][8192];  // [128 cols][64 k] bf16 swizzled

  int t = threadIdx.x;
  int w = t >> 6, l = t & 63;
  int lane16 = l & 15, g = l >> 4;
  int row0 = blockIdx.x * 128;
  int r = t >> 1, h = t & 1;       // staging: thread -> (row/col r, k-half h)
  int grow_stage = row0 + r;

  f32x4 acc[2][8];
#pragma unroll
  for (int rt = 0; rt < 2; rt++)
#pragma unroll
    for (int ct = 0; ct < 8; ct++) acc[rt][ct] = (f32x4){0.f, 0.f, 0.f, 0.f};

  float xf[32];
  uint4 wv[4];

  // prologue: load slab 0 into regs
  {
    const float4* src = (const float4*)(x + (size_t)grow_stage * INC + h * 32);
#pragma unroll
    for (int i = 0; i < 8; i++) {
      float4 v = (grow_stage < NN) ? src[i] : (float4){0, 0, 0, 0};
      xf[i * 4 + 0] = v.x; xf[i * 4 + 1] = v.y; xf[i * 4 + 2] = v.z; xf[i * 4 + 3] = v.w;
    }
    const uint4* wsrc = (const uint4*)(wt + (size_t)r * 512 + h * 32);
#pragma unroll
    for (int j = 0; j < 4; j++) wv[j] = wsrc[j];
  }

  for (int s = 0; s < 8; s++) {
    int buf = s & 1;
    // write staged regs -> LDS (swizzled)
    {
      unsigned pk[16];
#pragma unroll
      for (int q = 0; q < 16; q++)
        pk[q] = (unsigned)f2bf(xf[2 * q]) | ((unsigned)f2bf(xf[2 * q + 1]) << 16);
#pragma unroll
      for (int j = 0; j < 4; j++)
        *(uint4*)((char*)&xsb[buf][0] + SWZ(r, h * 64 + j * 16)) = ((uint4*)pk)[j];
#pragma unroll
      for (int j = 0; j < 4; j++)
        *(uint4*)((char*)&wsb[buf][0] + SWZ(r, h * 64 + j * 16)) = wv[j];
    }
    __syncthreads();
    // issue next slab's global loads (hide under MFMA)
    if (s < 7) {
      int k0 = (s + 1) * 64;
      const float4* src = (const float4*)(x + (size_t)grow_stage * INC + k0 + h * 32);
#pragma unroll
      for (int i = 0; i < 8; i++) {
        float4 v = (grow_stage < NN) ? src[i] : (float4){0, 0, 0, 0};
        xf[i * 4 + 0] = v.x; xf[i * 4 + 1] = v.y; xf[i * 4 + 2] = v.z; xf[i * 4 + 3] = v.w;
      }
      const uint4* wsrc = (const uint4*)(wt + (size_t)r * 512 + k0 + h * 32);
#pragma unroll
      for (int j = 0; j < 4; j++) wv[j] = wsrc[j];
    }
    // compute slab
#pragma unroll
    for (int s2 = 0; s2 < 2; s2++) {
      bf16x8 a[2], b[8];
#pragma unroll
      for (int rt = 0; rt < 2; rt++)
        a[rt] = *(const bf16x8*)((char*)&xsb[buf][0] +
                                 SWZ(w * 32 + rt * 16 + lane16, s2 * 64 + g * 16));
#pragma unroll
      for (int ct = 0; ct < 8; ct++)
        b[ct] = *(const bf16x8*)((char*)&wsb[buf][0] +
                                 SWZ(ct * 16 + lane16, s2 * 64 + g * 16));
#pragma unroll
      for (int rt = 0; rt < 2; rt++)
#pragma unroll
        for (int ct = 0; ct < 8; ct++)
          acc[rt][ct] = __builtin_amdgcn_mfma_f32_16x16x32_bf16(a[rt], b[ct], acc[rt][ct], 0, 0, 0);
    }
    __syncthreads();
  }

  // epilogue: acc -> LDS (bf16, swizzled 256B rows), then coalesced readback
  short* ob = (short*)&xsb[0][0];  // 32 KB = 128 rows x 128 cols bf16
#pragma unroll
  for (int rt = 0; rt < 2; rt++)
#pragma unroll
    for (int ct = 0; ct < 8; ct++)
#pragma unroll
      for (int i = 0; i < 4; i++) {
        int rloc = w * 32 + rt * 16 + g * 4 + i;
        int col = ct * 16 + lane16;
        *(short*)((char*)ob + SWZ2(rloc, col * 2)) = (short)f2bf(acc[rt][ct][i]);
      }
  __syncthreads();

  int grow = row0 + r;
  if (grow < NN) {
    float dv = dinv[grow];
    unsigned v[32];
#pragma unroll
    for (int j = 0; j < 8; j++)
      ((uint4*)v)[j] = *(const uint4*)((char*)ob + SWZ2(r, h * 128 + j * 16));
    if (h == 0) {
      // cols 0..63 -> hp words 0..31
#pragma unroll
      for (int q = 0; q < 32; q++) {
        unsigned o = (unsigned)f2bf(dv * bf_lo(v[q])) |
                     ((unsigned)f2bf(dv * bf_hi(v[q])) << 16);
        hp32[(size_t)grow * 50 + q] = o;
      }
    } else {
      // cols 64..99 -> hp words 32..49; cols 100,101 -> skip2
#pragma unroll
      for (int q = 0; q < 18; q++) {
        unsigned o = (unsigned)f2bf(dv * bf_lo(v[q])) |
                     ((unsigned)f2bf(dv * bf_hi(v[q])) << 16);
        hp32[(size_t)grow * 50 + 32 + q] = o;
      }
      skip2[(size_t)grow * 2 + 0] = bf_lo(v[18]) + bsk[0];
      skip2[(size_t)grow * 2 + 1] = bf_hi(v[18]) + bsk[1];
    }
  }
}

// ---------- 5) aggregate conv1: h1 = relu(dinv*(sum hp[src] + hp[i]) + b1) ----------
__global__ __launch_bounds__(256) void k_agg1(const unsigned* __restrict__ hp32,
                                              const int* __restrict__ csr,
                                              const int* __restrict__ row_start,
                                              const int* __restrict__ cnt,
                                              const float* __restrict__ dinv,
                                              const float* __restrict__ b1,
                                              float2* __restrict__ h1) {
  int node = blockIdx.x * 4 + (threadIdx.x >> 6);  // one wave per node
  int lane = threadIdx.x & 63;
  bool act = lane < 50;
  int start = row_start[node];
  int len = cnt[node];
  float a0 = 0.f, a1 = 0.f;
  if (act) {
    unsigned v = hp32[(size_t)node * 50 + lane];  // self-loop term
    a0 = bf_lo(v); a1 = bf_hi(v);
  }
  int s = (len > 0) ? csr[start] : 0;
  for (int j = 0; j < len; j++) {
    int snext = (j + 1 < len) ? csr[start + j + 1] : 0;
    if (act) {
      unsigned v = hp32[(size_t)s * 50 + lane];
      a0 += bf_lo(v); a1 += bf_hi(v);
    }
    s = snext;
  }
  if (act) {
    float dv = dinv[node];
    float r0 = fmaxf(fmaf(dv, a0, b1[2 * lane]), 0.f);
    float r1 = fmaxf(fmaf(dv, a1, b1[2 * lane + 1]), 0.f);
    h1[(size_t)node * 50 + lane] = make_float2(r0, r1);
  }
}

// ---------- 6) p = dinv * (h1 @ W2) ----------
__global__ __launch_bounds__(256) void k_gemm2(const float* __restrict__ h1,
                                               const float* __restrict__ W2,
                                               const float* __restrict__ dinv,
                                               float* __restrict__ p) {
  __shared__ float xs[128 * 101];
  __shared__ float w2s[200];
  int t = threadIdx.x;
  int r0 = blockIdx.x * 128;
  if (t < 200) w2s[t] = W2[t];
  for (int idx = t; idx < 128 * 100; idx += 256) {
    int r = idx / 100, f = idx - r * 100;
    int g = r0 + r;
    xs[r * 101 + f] = (g < NN) ? h1[(size_t)g * 100 + f] : 0.f;
  }
  __syncthreads();
  int r = t >> 1, c = t & 1;
  int g = r0 + r;
  if (g < NN) {
    float acc = 0.f;
#pragma unroll
    for (int f = 0; f < 100; f++)
      acc = fmaf(xs[r * 101 + f], w2s[2 * f + c], acc);
    p[(size_t)g * 2 + c] = dinv[g] * acc;
  }
}

// ---------- 7) conv2 aggregate + skip + log_softmax ----------
__global__ __launch_bounds__(256) void k_final(const float2* __restrict__ p,
                                               const int* __restrict__ csr,
                                               const int* __restrict__ row_start,
                                               const int* __restrict__ cnt,
                                               const float* __restrict__ dinv,
                                               const float* __restrict__ b2,
                                               const float2* __restrict__ skip2,
                                               float2* __restrict__ out) {
  int i = blockIdx.x * 256 + threadIdx.x;
  if (i >= NN) return;
  float2 pi = p[i];
  float a0 = pi.x, a1 = pi.y;  // self-loop
  int start = row_start[i], len = cnt[i];
  for (int j = 0; j < len; j++) {
    int s = csr[start + j];
    float2 ps = p[s];
    a0 += ps.x; a1 += ps.y;
  }
  float dv = dinv[i];
  float2 sk = skip2[i];
  float v0 = dv * a0 + b2[0] + sk.x;
  float v1 = dv * a1 + b2[1] + sk.y;
  float m = fmaxf(v0, v1);
  float lse = m + logf(expf(v0 - m) + expf(v1 - m));
  out[i] = make_float2(v0 - lse, v1 - lse);
}

extern "C" void kernel_launch(void* const* d_in, const int* in_sizes, int n_in,
                              void* d_out, int out_size, void* d_ws, size_t ws_size,
                              hipStream_t stream) {
  const float* x   = (const float*)d_in[0];
  const int*   ei  = (const int*)d_in[1];
  const float* W1  = (const float*)d_in[2];
  const float* b1  = (const float*)d_in[3];
  const float* W2  = (const float*)d_in[4];
  const float* b2  = (const float*)d_in[5];
  const float* Wsk = (const float*)d_in[6];
  const float* bsk = (const float*)d_in[7];
  float* out = (float*)d_out;

  char* w = (char*)d_ws;
  size_t off = 0;
  auto alloc = [&](size_t bytes) {
    void* ptr = w + off;
    off += (bytes + 255) & ~(size_t)255;
    return ptr;
  };
  int*      cnt   = (int*)alloc((size_t)NN * 4);
  int*      rs    = (int*)alloc((size_t)(NN + 1) * 4);
  int*      cur   = (int*)alloc((size_t)NN * 4);
  float*    dinv  = (float*)alloc((size_t)NN * 4);
  int*      csr   = (int*)alloc((size_t)EE * 4);
  unsigned* hp    = (unsigned*)alloc((size_t)NN * 50 * 4);  // bf16 x2 packed
  float*    skip2 = (float*)alloc((size_t)NN * 2 * 4);
  float*    h1    = (float*)alloc((size_t)NN * 100 * 4);
  float*    p     = (float*)alloc((size_t)NN * 2 * 4);
  short*    wt    = (short*)alloc((size_t)128 * 512 * 2);   // bf16 W^T padded

  hipMemsetAsync(cnt, 0, (size_t)NN * 4, stream);
  k_wprep<<<256, 256, 0, stream>>>(W1, Wsk, wt);
  k_hist<<<EE / 256, 256, 0, stream>>>(ei, cnt);
  k_scan<<<1, 1024, 0, stream>>>(cnt, rs, cur, dinv);
  k_fill<<<EE / 256, 256, 0, stream>>>(ei, cur, csr);
  k_gemm1m<<<(NN + 127) / 128, 256, 0, stream>>>(x, wt, bsk, dinv, hp, skip2);
  k_agg1<<<NN / 4, 256, 0, stream>>>(hp, csr, rs, cnt, dinv, b1, (float2*)h1);
  k_gemm2<<<(NN + 127) / 128, 256, 0, stream>>>(h1, W2, dinv, p);
  k_final<<<(NN + 255) / 256, 256, 0, stream>>>((const float2*)p, csr, rs, cnt,
                                                dinv, b2, (const float2*)skip2,
                                                (float2*)out);
}

// Round 11
// 735.673 us; speedup vs baseline: 3.4029x; 1.3390x over previous
//
#include <hip/hip_runtime.h>
#include <hip/hip_bf16.h>
#include <math.h>

#define NN 100000
#define EE 1600000
#define INC 512
#define HIDC 100
#define NCH 782  // ceil(NN/128)

typedef __attribute__((ext_vector_type(8))) short bf16x8;
typedef __attribute__((ext_vector_type(4))) float f32x4;

static __device__ __forceinline__ unsigned short f2bf(float f) {
  unsigned u = __float_as_uint(f);
  return (unsigned short)((u + (0x7fffu + ((u >> 16) & 1u))) >> 16);
}
static __device__ __forceinline__ float bf_lo(unsigned v) {
  return __uint_as_float(v << 16);
}
static __device__ __forceinline__ float bf_hi(unsigned v) {
  return __uint_as_float(v & 0xffff0000u);
}

// swizzle for [row][64] bf16 tiles (128 B/row): XOR chunk bits with row&7
#define SWZ(row, byteoff) (((row) * 128 + ((byteoff) ^ (((row) & 7) << 4))))
// swizzle for [row][128] bf16 output tile (256 B/row)
#define SWZ2(row, byteoff) (((row) * 256 + ((byteoff) ^ (((row) & 7) << 4))))

// ---------- 0) W prep: wt[c][k] = bf16(W1[k][c] | Ws[k][c-100] | 0), c<128 ----------
__global__ void k_wprep(const float* __restrict__ W1, const float* __restrict__ Wsk,
                        short* __restrict__ wt) {
  int t = blockIdx.x * 256 + threadIdx.x;  // 65536 total
  int c = t >> 9, k = t & 511;
  float v = 0.f;
  if (c < 100) v = W1[k * 100 + c];
  else if (c < 102) v = Wsk[k * 2 + (c - 100)];
  wt[c * 512 + k] = (short)f2bf(v);
}

// ---------- 1) histogram of dst ----------
__global__ void k_hist(const int* __restrict__ ei, int* __restrict__ cnt) {
  int e = blockIdx.x * 256 + threadIdx.x;
  if (e < EE) atomicAdd(&cnt[ei[EE + e]], 1);
}

// ---------- 2a) per-chunk sums (128 elems/chunk) ----------
__global__ __launch_bounds__(128) void k_chunksum(const int* __restrict__ cnt,
                                                  int* __restrict__ chunksum) {
  __shared__ int ws[2];
  int b = blockIdx.x;
  int i = b * 128 + threadIdx.x;
  int c = (i < NN) ? cnt[i] : 0;
  int l = threadIdx.x & 63, w = threadIdx.x >> 6;
#pragma unroll
  for (int off = 32; off > 0; off >>= 1) c += __shfl_down(c, off, 64);
  if (l == 0) ws[w] = c;
  __syncthreads();
  if (threadIdx.x == 0) chunksum[b] = ws[0] + ws[1];
}

// ---------- 2b) single-block scan over 782 chunk sums ----------
__global__ __launch_bounds__(1024) void k_scanchunks(const int* __restrict__ chunksum,
                                                     int* __restrict__ chunkbase) {
  __shared__ int s[1024];
  int t = threadIdx.x;
  s[t] = (t < NCH) ? chunksum[t] : 0;
  __syncthreads();
  for (int off = 1; off < 1024; off <<= 1) {
    int v = s[t];
    int u = (t >= off) ? s[t - off] : 0;
    __syncthreads();
    s[t] = v + u;
    __syncthreads();
  }
  if (t < NCH) chunkbase[t] = (t == 0) ? 0 : s[t - 1];
}

// ---------- 2c) emit row_start / cursor / dinv ----------
__global__ __launch_bounds__(128) void k_emit(const int* __restrict__ cnt,
                                              const int* __restrict__ chunkbase,
                                              int* __restrict__ row_start,
                                              int* __restrict__ cursor,
                                              float* __restrict__ dinv) {
  __shared__ int s[128];
  int b = blockIdx.x, t = threadIdx.x;
  int i = b * 128 + t;
  int c = (i < NN) ? cnt[i] : 0;
  s[t] = c;
  __syncthreads();
  for (int off = 1; off < 128; off <<= 1) {
    int v = s[t];
    int u = (t >= off) ? s[t - off] : 0;
    __syncthreads();
    s[t] = v + u;
    __syncthreads();
  }
  if (i < NN) {
    int excl = s[t] - c + chunkbase[b];
    row_start[i] = excl;
    cursor[i] = excl;
    dinv[i] = rsqrtf((float)(c + 1));  // +1 self-loop
  }
}

// ---------- 3) fill CSR (by dst) ----------
__global__ void k_fill(const int* __restrict__ ei, int* __restrict__ cursor,
                       int* __restrict__ csr) {
  int e = blockIdx.x * 256 + threadIdx.x;
  if (e < EE) {
    int d = ei[EE + e];
    int pos = atomicAdd(&cursor[d], 1);
    csr[pos] = ei[e];  // src
  }
}

// ---------- 4) MFMA GEMM: hp = bf16(dinv*(x@W1)), skip2 = x@Ws + bs ----------
// tile: 128 rows x 128 cols (cols 0-99 = W1, 100-101 = Ws, 102-127 pad)
// K = 512, BK = 64, double-buffered LDS, bf16 mfma_f32_16x16x32
__global__ __launch_bounds__(256) void k_gemm1m(const float* __restrict__ x,
                                                const short* __restrict__ wt,
                                                const float* __restrict__ bsk,
                                                const float* __restrict__ dinv,
                                                unsigned* __restrict__ hp32,
                                                float* __restrict__ skip2) {
  __shared__ short xsb[2][8192];  // [128 rows][64 k] bf16 swizzled, 16 KB each
  __shared__ short wsb[2][8192];  // [128 cols][64 k] bf16 swizzled

  int t = threadIdx.x;
  int w = t >> 6, l = t & 63;
  int lane16 = l & 15, g = l >> 4;
  int row0 = blockIdx.x * 128;
  int r = t >> 1, h = t & 1;       // staging: thread -> (row/col r, k-half h)
  int grow_stage = row0 + r;

  f32x4 acc[2][8];
#pragma unroll
  for (int rt = 0; rt < 2; rt++)
#pragma unroll
    for (int ct = 0; ct < 8; ct++) acc[rt][ct] = (f32x4){0.f, 0.f, 0.f, 0.f};

  float xf[32];
  uint4 wv[4];

  // prologue: load slab 0 into regs
  {
    const float4* src = (const float4*)(x + (size_t)grow_stage * INC + h * 32);
#pragma unroll
    for (int i = 0; i < 8; i++) {
      float4 v = (grow_stage < NN) ? src[i] : (float4){0, 0, 0, 0};
      xf[i * 4 + 0] = v.x; xf[i * 4 + 1] = v.y; xf[i * 4 + 2] = v.z; xf[i * 4 + 3] = v.w;
    }
    const uint4* wsrc = (const uint4*)(wt + (size_t)r * 512 + h * 32);
#pragma unroll
    for (int j = 0; j < 4; j++) wv[j] = wsrc[j];
  }

  for (int s = 0; s < 8; s++) {
    int buf = s & 1;
    // write staged regs -> LDS (swizzled)
    {
      unsigned pk[16];
#pragma unroll
      for (int q = 0; q < 16; q++)
        pk[q] = (unsigned)f2bf(xf[2 * q]) | ((unsigned)f2bf(xf[2 * q + 1]) << 16);
#pragma unroll
      for (int j = 0; j < 4; j++)
        *(uint4*)((char*)&xsb[buf][0] + SWZ(r, h * 64 + j * 16)) = ((uint4*)pk)[j];
#pragma unroll
      for (int j = 0; j < 4; j++)
        *(uint4*)((char*)&wsb[buf][0] + SWZ(r, h * 64 + j * 16)) = wv[j];
    }
    __syncthreads();
    // issue next slab's global loads (hide under MFMA)
    if (s < 7) {
      int k0 = (s + 1) * 64;
      const float4* src = (const float4*)(x + (size_t)grow_stage * INC + k0 + h * 32);
#pragma unroll
      for (int i = 0; i < 8; i++) {
        float4 v = (grow_stage < NN) ? src[i] : (float4){0, 0, 0, 0};
        xf[i * 4 + 0] = v.x; xf[i * 4 + 1] = v.y; xf[i * 4 + 2] = v.z; xf[i * 4 + 3] = v.w;
      }
      const uint4* wsrc = (const uint4*)(wt + (size_t)r * 512 + k0 + h * 32);
#pragma unroll
      for (int j = 0; j < 4; j++) wv[j] = wsrc[j];
    }
    // compute slab
#pragma unroll
    for (int s2 = 0; s2 < 2; s2++) {
      bf16x8 a[2], b[8];
#pragma unroll
      for (int rt = 0; rt < 2; rt++)
        a[rt] = *(const bf16x8*)((char*)&xsb[buf][0] +
                                 SWZ(w * 32 + rt * 16 + lane16, s2 * 64 + g * 16));
#pragma unroll
      for (int ct = 0; ct < 8; ct++)
        b[ct] = *(const bf16x8*)((char*)&wsb[buf][0] +
                                 SWZ(ct * 16 + lane16, s2 * 64 + g * 16));
#pragma unroll
      for (int rt = 0; rt < 2; rt++)
#pragma unroll
        for (int ct = 0; ct < 8; ct++)
          acc[rt][ct] = __builtin_amdgcn_mfma_f32_16x16x32_bf16(a[rt], b[ct], acc[rt][ct], 0, 0, 0);
    }
    __syncthreads();
  }

  // epilogue: acc -> LDS (bf16, swizzled 256B rows), then coalesced readback
  short* ob = (short*)&xsb[0][0];  // 32 KB = 128 rows x 128 cols bf16
#pragma unroll
  for (int rt = 0; rt < 2; rt++)
#pragma unroll
    for (int ct = 0; ct < 8; ct++)
#pragma unroll
      for (int i = 0; i < 4; i++) {
        int rloc = w * 32 + rt * 16 + g * 4 + i;
        int col = ct * 16 + lane16;
        *(short*)((char*)ob + SWZ2(rloc, col * 2)) = (short)f2bf(acc[rt][ct][i]);
      }
  __syncthreads();

  int grow = row0 + r;
  if (grow < NN) {
    float dv = dinv[grow];
    unsigned v[32];
#pragma unroll
    for (int j = 0; j < 8; j++)
      ((uint4*)v)[j] = *(const uint4*)((char*)ob + SWZ2(r, h * 128 + j * 16));
    if (h == 0) {
      // cols 0..63 -> hp words 0..31
#pragma unroll
      for (int q = 0; q < 32; q++) {
        unsigned o = (unsigned)f2bf(dv * bf_lo(v[q])) |
                     ((unsigned)f2bf(dv * bf_hi(v[q])) << 16);
        hp32[(size_t)grow * 50 + q] = o;
      }
    } else {
      // cols 64..99 -> hp words 32..49; cols 100,101 -> skip2
#pragma unroll
      for (int q = 0; q < 18; q++) {
        unsigned o = (unsigned)f2bf(dv * bf_lo(v[q])) |
                     ((unsigned)f2bf(dv * bf_hi(v[q])) << 16);
        hp32[(size_t)grow * 50 + 32 + q] = o;
      }
      skip2[(size_t)grow * 2 + 0] = bf_lo(v[18]) + bsk[0];
      skip2[(size_t)grow * 2 + 1] = bf_hi(v[18]) + bsk[1];
    }
  }
}

// ---------- 5) aggregate conv1: h1 = relu(dinv*(sum hp[src] + hp[i]) + b1) ----------
__global__ __launch_bounds__(256) void k_agg1(const unsigned* __restrict__ hp32,
                                              const int* __restrict__ csr,
                                              const int* __restrict__ row_start,
                                              const int* __restrict__ cnt,
                                              const float* __restrict__ dinv,
                                              const float* __restrict__ b1,
                                              float2* __restrict__ h1) {
  int node = blockIdx.x * 4 + (threadIdx.x >> 6);  // one wave per node
  int lane = threadIdx.x & 63;
  bool act = lane < 50;
  int start = row_start[node];
  int len = cnt[node];
  float a0 = 0.f, a1 = 0.f;
  if (act) {
    unsigned v = hp32[(size_t)node * 50 + lane];  // self-loop term
    a0 = bf_lo(v); a1 = bf_hi(v);
  }
  int s = (len > 0) ? csr[start] : 0;
  for (int j = 0; j < len; j++) {
    int snext = (j + 1 < len) ? csr[start + j + 1] : 0;
    if (act) {
      unsigned v = hp32[(size_t)s * 50 + lane];
      a0 += bf_lo(v); a1 += bf_hi(v);
    }
    s = snext;
  }
  if (act) {
    float dv = dinv[node];
    float r0 = fmaxf(fmaf(dv, a0, b1[2 * lane]), 0.f);
    float r1 = fmaxf(fmaf(dv, a1, b1[2 * lane + 1]), 0.f);
    h1[(size_t)node * 50 + lane] = make_float2(r0, r1);
  }
}

// ---------- 6) p = dinv * (h1 @ W2) ----------
__global__ __launch_bounds__(256) void k_gemm2(const float* __restrict__ h1,
                                               const float* __restrict__ W2,
                                               const float* __restrict__ dinv,
                                               float* __restrict__ p) {
  __shared__ float xs[128 * 101];
  __shared__ float w2s[200];
  int t = threadIdx.x;
  int r0 = blockIdx.x * 128;
  if (t < 200) w2s[t] = W2[t];
  for (int idx = t; idx < 128 * 100; idx += 256) {
    int r = idx / 100, f = idx - r * 100;
    int g = r0 + r;
    xs[r * 101 + f] = (g < NN) ? h1[(size_t)g * 100 + f] : 0.f;
  }
  __syncthreads();
  int r = t >> 1, c = t & 1;
  int g = r0 + r;
  if (g < NN) {
    float acc = 0.f;
#pragma unroll
    for (int f = 0; f < 100; f++)
      acc = fmaf(xs[r * 101 + f], w2s[2 * f + c], acc);
    p[(size_t)g * 2 + c] = dinv[g] * acc;
  }
}

// ---------- 7) conv2 aggregate + skip + log_softmax ----------
__global__ __launch_bounds__(256) void k_final(const float2* __restrict__ p,
                                               const int* __restrict__ csr,
                                               const int* __restrict__ row_start,
                                               const int* __restrict__ cnt,
                                               const float* __restrict__ dinv,
                                               const float* __restrict__ b2,
                                               const float2* __restrict__ skip2,
                                               float2* __restrict__ out) {
  int i = blockIdx.x * 256 + threadIdx.x;
  if (i >= NN) return;
  float2 pi = p[i];
  float a0 = pi.x, a1 = pi.y;  // self-loop
  int start = row_start[i], len = cnt[i];
  for (int j = 0; j < len; j++) {
    int s = csr[start + j];
    float2 ps = p[s];
    a0 += ps.x; a1 += ps.y;
  }
  float dv = dinv[i];
  float2 sk = skip2[i];
  float v0 = dv * a0 + b2[0] + sk.x;
  float v1 = dv * a1 + b2[1] + sk.y;
  float m = fmaxf(v0, v1);
  float lse = m + logf(expf(v0 - m) + expf(v1 - m));
  out[i] = make_float2(v0 - lse, v1 - lse);
}

extern "C" void kernel_launch(void* const* d_in, const int* in_sizes, int n_in,
                              void* d_out, int out_size, void* d_ws, size_t ws_size,
                              hipStream_t stream) {
  const float* x   = (const float*)d_in[0];
  const int*   ei  = (const int*)d_in[1];
  const float* W1  = (const float*)d_in[2];
  const float* b1  = (const float*)d_in[3];
  const float* W2  = (const float*)d_in[4];
  const float* b2  = (const float*)d_in[5];
  const float* Wsk = (const float*)d_in[6];
  const float* bsk = (const float*)d_in[7];
  float* out = (float*)d_out;

  char* w = (char*)d_ws;
  size_t off = 0;
  auto alloc = [&](size_t bytes) {
    void* ptr = w + off;
    off += (bytes + 255) & ~(size_t)255;
    return ptr;
  };
  int*      cnt   = (int*)alloc((size_t)NN * 4);
  int*      rs    = (int*)alloc((size_t)(NN + 1) * 4);
  int*      cur   = (int*)alloc((size_t)NN * 4);
  float*    dinv  = (float*)alloc((size_t)NN * 4);
  int*      csr   = (int*)alloc((size_t)EE * 4);
  unsigned* hp    = (unsigned*)alloc((size_t)NN * 50 * 4);  // bf16 x2 packed
  float*    skip2 = (float*)alloc((size_t)NN * 2 * 4);
  float*    h1    = (float*)alloc((size_t)NN * 100 * 4);
  float*    p     = (float*)alloc((size_t)NN * 2 * 4);
  short*    wt    = (short*)alloc((size_t)128 * 512 * 2);   // bf16 W^T padded
  int*      csum  = (int*)alloc((size_t)1024 * 4);
  int*      cbase = (int*)alloc((size_t)1024 * 4);

  hipMemsetAsync(cnt, 0, (size_t)NN * 4, stream);
  k_wprep<<<256, 256, 0, stream>>>(W1, Wsk, wt);
  k_hist<<<EE / 256, 256, 0, stream>>>(ei, cnt);
  k_chunksum<<<NCH, 128, 0, stream>>>(cnt, csum);
  k_scanchunks<<<1, 1024, 0, stream>>>(csum, cbase);
  k_emit<<<NCH, 128, 0, stream>>>(cnt, cbase, rs, cur, dinv);
  k_fill<<<EE / 256, 256, 0, stream>>>(ei, cur, csr);
  k_gemm1m<<<(NN + 127) / 128, 256, 0, stream>>>(x, wt, bsk, dinv, hp, skip2);
  k_agg1<<<NN / 4, 256, 0, stream>>>(hp, csr, rs, cnt, dinv, b1, (float2*)h1);
  k_gemm2<<<(NN + 127) / 128, 256, 0, stream>>>(h1, W2, dinv, p);
  k_final<<<(NN + 255) / 256, 256, 0, stream>>>((const float2*)p, csr, rs, cnt,
                                                dinv, b2, (const float2*)skip2,
                                                (float2*)out);
}

// Round 12
// 644.265 us; speedup vs baseline: 3.8857x; 1.1419x over previous
//
#include <hip/hip_runtime.h>
#include <hip/hip_bf16.h>
#include <math.h>

#define NN 100000
#define EE 1600000
#define INC 512
#define HIDC 100
#define NCH 782  // ceil(NN/128)

typedef __attribute__((ext_vector_type(8))) short bf16x8;
typedef __attribute__((ext_vector_type(4))) float f32x4;

static __device__ __forceinline__ unsigned short f2bf(float f) {
  unsigned u = __float_as_uint(f);
  return (unsigned short)((u + (0x7fffu + ((u >> 16) & 1u))) >> 16);
}
static __device__ __forceinline__ float bf_lo(unsigned v) {
  return __uint_as_float(v << 16);
}
static __device__ __forceinline__ float bf_hi(unsigned v) {
  return __uint_as_float(v & 0xffff0000u);
}

// swizzle for [row][64] bf16 tiles (128 B/row): XOR chunk bits with row&7
#define SWZ(row, byteoff) (((row) * 128 + ((byteoff) ^ (((row) & 7) << 4))))
// swizzle for [row][128] bf16 output tile (256 B/row)
#define SWZ2(row, byteoff) (((row) * 256 + ((byteoff) ^ (((row) & 7) << 4))))

// ---------- 0) W prep: wt[c][k] = bf16(W1[k][c] | Ws[k][c-100] | 0), c<128 ----------
__global__ void k_wprep(const float* __restrict__ W1, const float* __restrict__ Wsk,
                        short* __restrict__ wt) {
  int t = blockIdx.x * 256 + threadIdx.x;  // 65536 total
  int c = t >> 9, k = t & 511;
  float v = 0.f;
  if (c < 100) v = W1[k * 100 + c];
  else if (c < 102) v = Wsk[k * 2 + (c - 100)];
  wt[c * 512 + k] = (short)f2bf(v);
}

// ---------- 1) histogram of dst ----------
__global__ void k_hist(const int* __restrict__ ei, int* __restrict__ cnt) {
  int e = blockIdx.x * 256 + threadIdx.x;
  if (e < EE) atomicAdd(&cnt[ei[EE + e]], 1);
}

// ---------- 2a) per-chunk sums (128 elems/chunk) ----------
__global__ __launch_bounds__(128) void k_chunksum(const int* __restrict__ cnt,
                                                  int* __restrict__ chunksum) {
  __shared__ int ws[2];
  int b = blockIdx.x;
  int i = b * 128 + threadIdx.x;
  int c = (i < NN) ? cnt[i] : 0;
  int l = threadIdx.x & 63, w = threadIdx.x >> 6;
#pragma unroll
  for (int off = 32; off > 0; off >>= 1) c += __shfl_down(c, off, 64);
  if (l == 0) ws[w] = c;
  __syncthreads();
  if (threadIdx.x == 0) chunksum[b] = ws[0] + ws[1];
}

// ---------- 2b) single-block scan over 782 chunk sums ----------
__global__ __launch_bounds__(1024) void k_scanchunks(const int* __restrict__ chunksum,
                                                     int* __restrict__ chunkbase) {
  __shared__ int s[1024];
  int t = threadIdx.x;
  s[t] = (t < NCH) ? chunksum[t] : 0;
  __syncthreads();
  for (int off = 1; off < 1024; off <<= 1) {
    int v = s[t];
    int u = (t >= off) ? s[t - off] : 0;
    __syncthreads();
    s[t] = v + u;
    __syncthreads();
  }
  if (t < NCH) chunkbase[t] = (t == 0) ? 0 : s[t - 1];
}

// ---------- 2c) emit row_start / cursor / dinv ----------
__global__ __launch_bounds__(128) void k_emit(const int* __restrict__ cnt,
                                              const int* __restrict__ chunkbase,
                                              int* __restrict__ row_start,
                                              int* __restrict__ cursor,
                                              float* __restrict__ dinv) {
  __shared__ int s[128];
  int b = blockIdx.x, t = threadIdx.x;
  int i = b * 128 + t;
  int c = (i < NN) ? cnt[i] : 0;
  s[t] = c;
  __syncthreads();
  for (int off = 1; off < 128; off <<= 1) {
    int v = s[t];
    int u = (t >= off) ? s[t - off] : 0;
    __syncthreads();
    s[t] = v + u;
    __syncthreads();
  }
  if (i < NN) {
    int excl = s[t] - c + chunkbase[b];
    row_start[i] = excl;
    cursor[i] = excl;
    dinv[i] = rsqrtf((float)(c + 1));  // +1 self-loop
  }
}

// ---------- 3) fill CSR (by dst) ----------
__global__ void k_fill(const int* __restrict__ ei, int* __restrict__ cursor,
                       int* __restrict__ csr) {
  int e = blockIdx.x * 256 + threadIdx.x;
  if (e < EE) {
    int d = ei[EE + e];
    int pos = atomicAdd(&cursor[d], 1);
    csr[pos] = ei[e];  // src
  }
}

// ---------- 4) MFMA GEMM: hp = bf16(dinv*(x@W1)), skip2 = x@Ws + bs ----------
// tile: 128 rows x 128 cols (cols 0-99 = W1, 100-101 = Ws, 102-127 pad)
// K = 512, BK = 64, double-buffered LDS, bf16 mfma_f32_16x16x32
__global__ __launch_bounds__(256) void k_gemm1m(const float* __restrict__ x,
                                                const short* __restrict__ wt,
                                                const float* __restrict__ bsk,
                                                const float* __restrict__ dinv,
                                                unsigned* __restrict__ hp32,
                                                float* __restrict__ skip2) {
  __shared__ short xsb[2][8192];  // [128 rows][64 k] bf16 swizzled, 16 KB each
  __shared__ short wsb[2][8192];  // [128 cols][64 k] bf16 swizzled

  int t = threadIdx.x;
  int w = t >> 6, l = t & 63;
  int lane16 = l & 15, g = l >> 4;
  int row0 = blockIdx.x * 128;
  int r = t >> 1, h = t & 1;       // staging: thread -> (row/col r, k-half h)
  int grow_stage = row0 + r;

  f32x4 acc[2][8];
#pragma unroll
  for (int rt = 0; rt < 2; rt++)
#pragma unroll
    for (int ct = 0; ct < 8; ct++) acc[rt][ct] = (f32x4){0.f, 0.f, 0.f, 0.f};

  float xf[32];
  uint4 wv[4];

  // prologue: load slab 0 into regs
  {
    const float4* src = (const float4*)(x + (size_t)grow_stage * INC + h * 32);
#pragma unroll
    for (int i = 0; i < 8; i++) {
      float4 v = (grow_stage < NN) ? src[i] : (float4){0, 0, 0, 0};
      xf[i * 4 + 0] = v.x; xf[i * 4 + 1] = v.y; xf[i * 4 + 2] = v.z; xf[i * 4 + 3] = v.w;
    }
    const uint4* wsrc = (const uint4*)(wt + (size_t)r * 512 + h * 32);
#pragma unroll
    for (int j = 0; j < 4; j++) wv[j] = wsrc[j];
  }

  for (int s = 0; s < 8; s++) {
    int buf = s & 1;
    // write staged regs -> LDS (swizzled)
    {
      unsigned pk[16];
#pragma unroll
      for (int q = 0; q < 16; q++)
        pk[q] = (unsigned)f2bf(xf[2 * q]) | ((unsigned)f2bf(xf[2 * q + 1]) << 16);
#pragma unroll
      for (int j = 0; j < 4; j++)
        *(uint4*)((char*)&xsb[buf][0] + SWZ(r, h * 64 + j * 16)) = ((uint4*)pk)[j];
#pragma unroll
      for (int j = 0; j < 4; j++)
        *(uint4*)((char*)&wsb[buf][0] + SWZ(r, h * 64 + j * 16)) = wv[j];
    }
    __syncthreads();
    // issue next slab's global loads (hide under MFMA)
    if (s < 7) {
      int k0 = (s + 1) * 64;
      const float4* src = (const float4*)(x + (size_t)grow_stage * INC + k0 + h * 32);
#pragma unroll
      for (int i = 0; i < 8; i++) {
        float4 v = (grow_stage < NN) ? src[i] : (float4){0, 0, 0, 0};
        xf[i * 4 + 0] = v.x; xf[i * 4 + 1] = v.y; xf[i * 4 + 2] = v.z; xf[i * 4 + 3] = v.w;
      }
      const uint4* wsrc = (const uint4*)(wt + (size_t)r * 512 + k0 + h * 32);
#pragma unroll
      for (int j = 0; j < 4; j++) wv[j] = wsrc[j];
    }
    // compute slab
#pragma unroll
    for (int s2 = 0; s2 < 2; s2++) {
      bf16x8 a[2], b[8];
#pragma unroll
      for (int rt = 0; rt < 2; rt++)
        a[rt] = *(const bf16x8*)((char*)&xsb[buf][0] +
                                 SWZ(w * 32 + rt * 16 + lane16, s2 * 64 + g * 16));
#pragma unroll
      for (int ct = 0; ct < 8; ct++)
        b[ct] = *(const bf16x8*)((char*)&wsb[buf][0] +
                                 SWZ(ct * 16 + lane16, s2 * 64 + g * 16));
#pragma unroll
      for (int rt = 0; rt < 2; rt++)
#pragma unroll
        for (int ct = 0; ct < 8; ct++)
          acc[rt][ct] = __builtin_amdgcn_mfma_f32_16x16x32_bf16(a[rt], b[ct], acc[rt][ct], 0, 0, 0);
    }
    __syncthreads();
  }

  // epilogue: acc -> LDS (bf16, swizzled 256B rows), then coalesced readback
  short* ob = (short*)&xsb[0][0];  // 32 KB = 128 rows x 128 cols bf16
#pragma unroll
  for (int rt = 0; rt < 2; rt++)
#pragma unroll
    for (int ct = 0; ct < 8; ct++)
#pragma unroll
      for (int i = 0; i < 4; i++) {
        int rloc = w * 32 + rt * 16 + g * 4 + i;
        int col = ct * 16 + lane16;
        *(short*)((char*)ob + SWZ2(rloc, col * 2)) = (short)f2bf(acc[rt][ct][i]);
      }
  __syncthreads();

  int grow = row0 + r;
  if (grow < NN) {
    float dv = dinv[grow];
    unsigned v[32];
#pragma unroll
    for (int j = 0; j < 8; j++)
      ((uint4*)v)[j] = *(const uint4*)((char*)ob + SWZ2(r, h * 128 + j * 16));
    if (h == 0) {
      // cols 0..63 -> hp words 0..31
#pragma unroll
      for (int q = 0; q < 32; q++) {
        unsigned o = (unsigned)f2bf(dv * bf_lo(v[q])) |
                     ((unsigned)f2bf(dv * bf_hi(v[q])) << 16);
        hp32[(size_t)grow * 50 + q] = o;
      }
    } else {
      // cols 64..99 -> hp words 32..49; cols 100,101 -> skip2
#pragma unroll
      for (int q = 0; q < 18; q++) {
        unsigned o = (unsigned)f2bf(dv * bf_lo(v[q])) |
                     ((unsigned)f2bf(dv * bf_hi(v[q])) << 16);
        hp32[(size_t)grow * 50 + 32 + q] = o;
      }
      skip2[(size_t)grow * 2 + 0] = bf_lo(v[18]) + bsk[0];
      skip2[(size_t)grow * 2 + 1] = bf_hi(v[18]) + bsk[1];
    }
  }
}

// ---------- 5) aggregate conv1: h1 = relu(dinv*(sum hp[src] + hp[i]) + b1) ----------
// one wave per node; edge loop unrolled x8 -> 8 independent 200B gathers in flight
__global__ __launch_bounds__(256) void k_agg1(const unsigned* __restrict__ hp32,
                                              const int* __restrict__ csr,
                                              const int* __restrict__ row_start,
                                              const int* __restrict__ cnt,
                                              const float* __restrict__ dinv,
                                              const float* __restrict__ b1,
                                              float2* __restrict__ h1) {
  int node = blockIdx.x * 4 + (threadIdx.x >> 6);  // one wave per node
  int lane = threadIdx.x & 63;
  bool act = lane < 50;
  int start = row_start[node];
  int len = cnt[node];
  float a0 = 0.f, a1 = 0.f;
  if (act) {
    unsigned v = hp32[(size_t)node * 50 + lane];  // self-loop term
    a0 = bf_lo(v); a1 = bf_hi(v);
  }
  int j = 0;
  for (; j + 8 <= len; j += 8) {
    int s0 = csr[start + j + 0], s1 = csr[start + j + 1];
    int s2 = csr[start + j + 2], s3 = csr[start + j + 3];
    int s4 = csr[start + j + 4], s5 = csr[start + j + 5];
    int s6 = csr[start + j + 6], s7 = csr[start + j + 7];
    if (act) {
      unsigned v0 = hp32[(size_t)s0 * 50 + lane];
      unsigned v1 = hp32[(size_t)s1 * 50 + lane];
      unsigned v2 = hp32[(size_t)s2 * 50 + lane];
      unsigned v3 = hp32[(size_t)s3 * 50 + lane];
      unsigned v4 = hp32[(size_t)s4 * 50 + lane];
      unsigned v5 = hp32[(size_t)s5 * 50 + lane];
      unsigned v6 = hp32[(size_t)s6 * 50 + lane];
      unsigned v7 = hp32[(size_t)s7 * 50 + lane];
      a0 += bf_lo(v0) + bf_lo(v1) + bf_lo(v2) + bf_lo(v3) +
            bf_lo(v4) + bf_lo(v5) + bf_lo(v6) + bf_lo(v7);
      a1 += bf_hi(v0) + bf_hi(v1) + bf_hi(v2) + bf_hi(v3) +
            bf_hi(v4) + bf_hi(v5) + bf_hi(v6) + bf_hi(v7);
    }
  }
  for (; j < len; j++) {
    int s = csr[start + j];
    if (act) {
      unsigned v = hp32[(size_t)s * 50 + lane];
      a0 += bf_lo(v); a1 += bf_hi(v);
    }
  }
  if (act) {
    float dv = dinv[node];
    float r0 = fmaxf(fmaf(dv, a0, b1[2 * lane]), 0.f);
    float r1 = fmaxf(fmaf(dv, a1, b1[2 * lane + 1]), 0.f);
    h1[(size_t)node * 50 + lane] = make_float2(r0, r1);
  }
}

// ---------- 6) p = dinv * (h1 @ W2) ----------
__global__ __launch_bounds__(256) void k_gemm2(const float* __restrict__ h1,
                                               const float* __restrict__ W2,
                                               const float* __restrict__ dinv,
                                               float* __restrict__ p) {
  __shared__ float xs[128 * 101];
  __shared__ float w2s[200];
  int t = threadIdx.x;
  int r0 = blockIdx.x * 128;
  if (t < 200) w2s[t] = W2[t];
  for (int idx = t; idx < 128 * 100; idx += 256) {
    int r = idx / 100, f = idx - r * 100;
    int g = r0 + r;
    xs[r * 101 + f] = (g < NN) ? h1[(size_t)g * 100 + f] : 0.f;
  }
  __syncthreads();
  int r = t >> 1, c = t & 1;
  int g = r0 + r;
  if (g < NN) {
    float acc = 0.f;
#pragma unroll
    for (int f = 0; f < 100; f++)
      acc = fmaf(xs[r * 101 + f], w2s[2 * f + c], acc);
    p[(size_t)g * 2 + c] = dinv[g] * acc;
  }
}

// ---------- 7) conv2 aggregate + skip + log_softmax ----------
// per-thread node; edge loop unrolled x4 (p table 800KB, mostly L2-resident)
__global__ __launch_bounds__(256) void k_final(const float2* __restrict__ p,
                                               const int* __restrict__ csr,
                                               const int* __restrict__ row_start,
                                               const int* __restrict__ cnt,
                                               const float* __restrict__ dinv,
                                               const float* __restrict__ b2,
                                               const float2* __restrict__ skip2,
                                               float2* __restrict__ out) {
  int i = blockIdx.x * 256 + threadIdx.x;
  if (i >= NN) return;
  float2 pi = p[i];
  float a0 = pi.x, a1 = pi.y;  // self-loop
  int start = row_start[i], len = cnt[i];
  int j = 0;
  for (; j + 4 <= len; j += 4) {
    int s0 = csr[start + j + 0], s1 = csr[start + j + 1];
    int s2 = csr[start + j + 2], s3 = csr[start + j + 3];
    float2 p0 = p[s0], p1 = p[s1], p2 = p[s2], p3 = p[s3];
    a0 += p0.x + p1.x + p2.x + p3.x;
    a1 += p0.y + p1.y + p2.y + p3.y;
  }
  for (; j < len; j++) {
    int s = csr[start + j];
    float2 ps = p[s];
    a0 += ps.x; a1 += ps.y;
  }
  float dv = dinv[i];
  float2 sk = skip2[i];
  float v0 = dv * a0 + b2[0] + sk.x;
  float v1 = dv * a1 + b2[1] + sk.y;
  float m = fmaxf(v0, v1);
  float lse = m + logf(expf(v0 - m) + expf(v1 - m));
  out[i] = make_float2(v0 - lse, v1 - lse);
}

extern "C" void kernel_launch(void* const* d_in, const int* in_sizes, int n_in,
                              void* d_out, int out_size, void* d_ws, size_t ws_size,
                              hipStream_t stream) {
  const float* x   = (const float*)d_in[0];
  const int*   ei  = (const int*)d_in[1];
  const float* W1  = (const float*)d_in[2];
  const float* b1  = (const float*)d_in[3];
  const float* W2  = (const float*)d_in[4];
  const float* b2  = (const float*)d_in[5];
  const float* Wsk = (const float*)d_in[6];
  const float* bsk = (const float*)d_in[7];
  float* out = (float*)d_out;

  char* w = (char*)d_ws;
  size_t off = 0;
  auto alloc = [&](size_t bytes) {
    void* ptr = w + off;
    off += (bytes + 255) & ~(size_t)255;
    return ptr;
  };
  int*      cnt   = (int*)alloc((size_t)NN * 4);
  int*      rs    = (int*)alloc((size_t)(NN + 1) * 4);
  int*      cur   = (int*)alloc((size_t)NN * 4);
  float*    dinv  = (float*)alloc((size_t)NN * 4);
  int*      csr   = (int*)alloc((size_t)EE * 4);
  unsigned* hp    = (unsigned*)alloc((size_t)NN * 50 * 4);  // bf16 x2 packed
  float*    skip2 = (float*)alloc((size_t)NN * 2 * 4);
  float*    h1    = (float*)alloc((size_t)NN * 100 * 4);
  float*    p     = (float*)alloc((size_t)NN * 2 * 4);
  short*    wt    = (short*)alloc((size_t)128 * 512 * 2);   // bf16 W^T padded
  int*      csum  = (int*)alloc((size_t)1024 * 4);
  int*      cbase = (int*)alloc((size_t)1024 * 4);

  hipMemsetAsync(cnt, 0, (size_t)NN * 4, stream);
  k_wprep<<<256, 256, 0, stream>>>(W1, Wsk, wt);
  k_hist<<<EE / 256, 256, 0, stream>>>(ei, cnt);
  k_chunksum<<<NCH, 128, 0, stream>>>(cnt, csum);
  k_scanchunks<<<1, 1024, 0, stream>>>(csum, cbase);
  k_emit<<<NCH, 128, 0, stream>>>(cnt, cbase, rs, cur, dinv);
  k_fill<<<EE / 256, 256, 0, stream>>>(ei, cur, csr);
  k_gemm1m<<<(NN + 127) / 128, 256, 0, stream>>>(x, wt, bsk, dinv, hp, skip2);
  k_agg1<<<NN / 4, 256, 0, stream>>>(hp, csr, rs, cnt, dinv, b1, (float2*)h1);
  k_gemm2<<<(NN + 127) / 128, 256, 0, stream>>>(h1, W2, dinv, p);
  k_final<<<(NN + 255) / 256, 256, 0, stream>>>((const float2*)p, csr, rs, cnt,
                                                dinv, b2, (const float2*)skip2,
                                                (float2*)out);
}

// Round 14
// 633.945 us; speedup vs baseline: 3.9489x; 1.0163x over previous
//
#include <hip/hip_runtime.h>
#include <hip/hip_bf16.h>
#include <math.h>

#define NN 100000
#define EE 1600000
#define INC 512
#define HIDC 100
#define NCH 782  // ceil(NN/128)

typedef __attribute__((ext_vector_type(8))) short bf16x8;
typedef __attribute__((ext_vector_type(4))) float f32x4;

static __device__ __forceinline__ unsigned short f2bf(float f) {
  unsigned u = __float_as_uint(f);
  return (unsigned short)((u + (0x7fffu + ((u >> 16) & 1u))) >> 16);
}
static __device__ __forceinline__ float bf_lo(unsigned v) {
  return __uint_as_float(v << 16);
}
static __device__ __forceinline__ float bf_hi(unsigned v) {
  return __uint_as_float(v & 0xffff0000u);
}

// swizzle for [row][64] bf16 tiles (128 B/row): XOR chunk bits with row&7
#define SWZ(row, byteoff) (((row) * 128 + ((byteoff) ^ (((row) & 7) << 4))))
// swizzle for [row][128] bf16 output tile (256 B/row)
#define SWZ2(row, byteoff) (((row) * 256 + ((byteoff) ^ (((row) & 7) << 4))))

// ---------- 0) W prep: wt[c][k] = bf16(W1[k][c] | Ws[k][c-100] | 0), c<128 ----------
__global__ void k_wprep(const float* __restrict__ W1, const float* __restrict__ Wsk,
                        short* __restrict__ wt) {
  int t = blockIdx.x * 256 + threadIdx.x;  // 65536 total
  int c = t >> 9, k = t & 511;
  float v = 0.f;
  if (c < 100) v = W1[k * 100 + c];
  else if (c < 102) v = Wsk[k * 2 + (c - 100)];
  wt[c * 512 + k] = (short)f2bf(v);
}

// ---------- 1) histogram of dst (fire-and-forget atomics) ----------
__global__ void k_hist(const int* __restrict__ ei, int* __restrict__ cnt) {
  int e = blockIdx.x * 256 + threadIdx.x;
  if (e < EE) atomicAdd(&cnt[ei[EE + e]], 1);
}

// ---------- 2a) per-chunk sums (128 elems/chunk) ----------
__global__ __launch_bounds__(128) void k_chunksum(const int* __restrict__ cnt,
                                                  int* __restrict__ chunksum) {
  __shared__ int ws[2];
  int b = blockIdx.x;
  int i = b * 128 + threadIdx.x;
  int c = (i < NN) ? cnt[i] : 0;
  int l = threadIdx.x & 63, w = threadIdx.x >> 6;
#pragma unroll
  for (int off = 32; off > 0; off >>= 1) c += __shfl_down(c, off, 64);
  if (l == 0) ws[w] = c;
  __syncthreads();
  if (threadIdx.x == 0) chunksum[b] = ws[0] + ws[1];
}

// ---------- 2b) single-block scan over 782 chunk sums ----------
__global__ __launch_bounds__(1024) void k_scanchunks(const int* __restrict__ chunksum,
                                                     int* __restrict__ chunkbase) {
  __shared__ int s[1024];
  int t = threadIdx.x;
  s[t] = (t < NCH) ? chunksum[t] : 0;
  __syncthreads();
  for (int off = 1; off < 1024; off <<= 1) {
    int v = s[t];
    int u = (t >= off) ? s[t - off] : 0;
    __syncthreads();
    s[t] = v + u;
    __syncthreads();
  }
  if (t < NCH) chunkbase[t] = (t == 0) ? 0 : s[t - 1];
}

// ---------- 2c) emit row_start / cursor / dinv ----------
__global__ __launch_bounds__(128) void k_emit(const int* __restrict__ cnt,
                                              const int* __restrict__ chunkbase,
                                              int* __restrict__ row_start,
                                              int* __restrict__ cursor,
                                              float* __restrict__ dinv) {
  __shared__ int s[128];
  int b = blockIdx.x, t = threadIdx.x;
  int i = b * 128 + t;
  int c = (i < NN) ? cnt[i] : 0;
  s[t] = c;
  __syncthreads();
  for (int off = 1; off < 128; off <<= 1) {
    int v = s[t];
    int u = (t >= off) ? s[t - off] : 0;
    __syncthreads();
    s[t] = v + u;
    __syncthreads();
  }
  if (i < NN) {
    int excl = s[t] - c + chunkbase[b];
    row_start[i] = excl;
    cursor[i] = excl;
    dinv[i] = rsqrtf((float)(c + 1));  // +1 self-loop
  }
}

// ---------- 3) fill CSR (by dst); x8 unroll -> 8 returning atomics in flight ----------
__global__ __launch_bounds__(256) void k_fill(const int* __restrict__ ei,
                                              int* __restrict__ cursor,
                                              int* __restrict__ csr) {
  int base = blockIdx.x * 2048 + threadIdx.x;
  int e[8], d[8], s[8], pos[8];
#pragma unroll
  for (int u = 0; u < 8; u++) e[u] = base + u * 256;
#pragma unroll
  for (int u = 0; u < 8; u++) {
    d[u] = (e[u] < EE) ? ei[EE + e[u]] : -1;
    s[u] = (e[u] < EE) ? ei[e[u]] : 0;
  }
#pragma unroll
  for (int u = 0; u < 8; u++)
    if (d[u] >= 0) pos[u] = atomicAdd(&cursor[d[u]], 1);
#pragma unroll
  for (int u = 0; u < 8; u++)
    if (d[u] >= 0) csr[pos[u]] = s[u];
}

// ---------- 4) MFMA GEMM: hp = bf16(dinv*(x@W1)), skip2 = x@Ws + bs ----------
// tile: 128 rows x 128 cols (cols 0-99 = W1, 100-101 = Ws, 102-127 pad)
// K = 512, BK = 64, double-buffered LDS, bf16 mfma_f32_16x16x32
__global__ __launch_bounds__(256) void k_gemm1m(const float* __restrict__ x,
                                                const short* __restrict__ wt,
                                                const float* __restrict__ bsk,
                                                const float* __restrict__ dinv,
                                                unsigned* __restrict__ hp32,
                                                float* __restrict__ skip2) {
  __shared__ short xsb[2][8192];  // [128 rows][64 k] bf16 swizzled, 16 KB each
  __shared__ short wsb[2][8192];  // [128 cols][64 k] bf16 swizzled

  int t = threadIdx.x;
  int w = t >> 6, l = t & 63;
  int lane16 = l & 15, g = l >> 4;
  int row0 = blockIdx.x * 128;
  int r = t >> 1, h = t & 1;       // staging: thread -> (row/col r, k-half h)
  int grow_stage = row0 + r;

  f32x4 acc[2][8];
#pragma unroll
  for (int rt = 0; rt < 2; rt++)
#pragma unroll
    for (int ct = 0; ct < 8; ct++) acc[rt][ct] = (f32x4){0.f, 0.f, 0.f, 0.f};

  float xf[32];
  uint4 wv[4];

  // prologue: load slab 0 into regs
  {
    const float4* src = (const float4*)(x + (size_t)grow_stage * INC + h * 32);
#pragma unroll
    for (int i = 0; i < 8; i++) {
      float4 v = (grow_stage < NN) ? src[i] : (float4){0, 0, 0, 0};
      xf[i * 4 + 0] = v.x; xf[i * 4 + 1] = v.y; xf[i * 4 + 2] = v.z; xf[i * 4 + 3] = v.w;
    }
    const uint4* wsrc = (const uint4*)(wt + (size_t)r * 512 + h * 32);
#pragma unroll
    for (int j = 0; j < 4; j++) wv[j] = wsrc[j];
  }

  for (int s = 0; s < 8; s++) {
    int buf = s & 1;
    // write staged regs -> LDS (swizzled)
    {
      unsigned pk[16];
#pragma unroll
      for (int q = 0; q < 16; q++)
        pk[q] = (unsigned)f2bf(xf[2 * q]) | ((unsigned)f2bf(xf[2 * q + 1]) << 16);
#pragma unroll
      for (int j = 0; j < 4; j++)
        *(uint4*)((char*)&xsb[buf][0] + SWZ(r, h * 64 + j * 16)) = ((uint4*)pk)[j];
#pragma unroll
      for (int j = 0; j < 4; j++)
        *(uint4*)((char*)&wsb[buf][0] + SWZ(r, h * 64 + j * 16)) = wv[j];
    }
    __syncthreads();
    // issue next slab's global loads (hide under MFMA)
    if (s < 7) {
      int k0 = (s + 1) * 64;
      const float4* src = (const float4*)(x + (size_t)grow_stage * INC + k0 + h * 32);
#pragma unroll
      for (int i = 0; i < 8; i++) {
        float4 v = (grow_stage < NN) ? src[i] : (float4){0, 0, 0, 0};
        xf[i * 4 + 0] = v.x; xf[i * 4 + 1] = v.y; xf[i * 4 + 2] = v.z; xf[i * 4 + 3] = v.w;
      }
      const uint4* wsrc = (const uint4*)(wt + (size_t)r * 512 + k0 + h * 32);
#pragma unroll
      for (int j = 0; j < 4; j++) wv[j] = wsrc[j];
    }
    // compute slab
#pragma unroll
    for (int s2 = 0; s2 < 2; s2++) {
      bf16x8 a[2], b[8];
#pragma unroll
      for (int rt = 0; rt < 2; rt++)
        a[rt] = *(const bf16x8*)((char*)&xsb[buf][0] +
                                 SWZ(w * 32 + rt * 16 + lane16, s2 * 64 + g * 16));
#pragma unroll
      for (int ct = 0; ct < 8; ct++)
        b[ct] = *(const bf16x8*)((char*)&wsb[buf][0] +
                                 SWZ(ct * 16 + lane16, s2 * 64 + g * 16));
#pragma unroll
      for (int rt = 0; rt < 2; rt++)
#pragma unroll
        for (int ct = 0; ct < 8; ct++)
          acc[rt][ct] = __builtin_amdgcn_mfma_f32_16x16x32_bf16(a[rt], b[ct], acc[rt][ct], 0, 0, 0);
    }
    __syncthreads();
  }

  // epilogue: acc -> LDS (bf16, swizzled 256B rows), then coalesced readback
  short* ob = (short*)&xsb[0][0];  // 32 KB = 128 rows x 128 cols bf16
#pragma unroll
  for (int rt = 0; rt < 2; rt++)
#pragma unroll
    for (int ct = 0; ct < 8; ct++)
#pragma unroll
      for (int i = 0; i < 4; i++) {
        int rloc = w * 32 + rt * 16 + g * 4 + i;
        int col = ct * 16 + lane16;
        *(short*)((char*)ob + SWZ2(rloc, col * 2)) = (short)f2bf(acc[rt][ct][i]);
      }
  __syncthreads();

  int grow = row0 + r;
  if (grow < NN) {
    float dv = dinv[grow];
    unsigned v[32];
#pragma unroll
    for (int j = 0; j < 8; j++)
      ((uint4*)v)[j] = *(const uint4*)((char*)ob + SWZ2(r, h * 128 + j * 16));
    if (h == 0) {
      // cols 0..63 -> hp words 0..31
#pragma unroll
      for (int q = 0; q < 32; q++) {
        unsigned o = (unsigned)f2bf(dv * bf_lo(v[q])) |
                     ((unsigned)f2bf(dv * bf_hi(v[q])) << 16);
        hp32[(size_t)grow * 50 + q] = o;
      }
    } else {
      // cols 64..99 -> hp words 32..49; cols 100,101 -> skip2
#pragma unroll
      for (int q = 0; q < 18; q++) {
        unsigned o = (unsigned)f2bf(dv * bf_lo(v[q])) |
                     ((unsigned)f2bf(dv * bf_hi(v[q])) << 16);
        hp32[(size_t)grow * 50 + 32 + q] = o;
      }
      skip2[(size_t)grow * 2 + 0] = bf_lo(v[18]) + bsk[0];
      skip2[(size_t)grow * 2 + 1] = bf_hi(v[18]) + bsk[1];
    }
  }
}

// ---------- 5) aggregate conv1: h1 = relu(dinv*(sum hp[src] + hp[i]) + b1) ----------
// one wave per node; edge loop unrolled x8 -> 8 independent 200B gathers in flight
__global__ __launch_bounds__(256) void k_agg1(const unsigned* __restrict__ hp32,
                                              const int* __restrict__ csr,
                                              const int* __restrict__ row_start,
                                              const int* __restrict__ cnt,
                                              const float* __restrict__ dinv,
                                              const float* __restrict__ b1,
                                              float2* __restrict__ h1) {
  int node = blockIdx.x * 4 + (threadIdx.x >> 6);  // one wave per node
  int lane = threadIdx.x & 63;
  bool act = lane < 50;
  int start = row_start[node];
  int len = cnt[node];
  float a0 = 0.f, a1 = 0.f;
  if (act) {
    unsigned v = hp32[(size_t)node * 50 + lane];  // self-loop term
    a0 = bf_lo(v); a1 = bf_hi(v);
  }
  int j = 0;
  for (; j + 8 <= len; j += 8) {
    int s0 = csr[start + j + 0], s1 = csr[start + j + 1];
    int s2 = csr[start + j + 2], s3 = csr[start + j + 3];
    int s4 = csr[start + j + 4], s5 = csr[start + j + 5];
    int s6 = csr[start + j + 6], s7 = csr[start + j + 7];
    if (act) {
      unsigned v0 = hp32[(size_t)s0 * 50 + lane];
      unsigned v1 = hp32[(size_t)s1 * 50 + lane];
      unsigned v2 = hp32[(size_t)s2 * 50 + lane];
      unsigned v3 = hp32[(size_t)s3 * 50 + lane];
      unsigned v4 = hp32[(size_t)s4 * 50 + lane];
      unsigned v5 = hp32[(size_t)s5 * 50 + lane];
      unsigned v6 = hp32[(size_t)s6 * 50 + lane];
      unsigned v7 = hp32[(size_t)s7 * 50 + lane];
      a0 += bf_lo(v0) + bf_lo(v1) + bf_lo(v2) + bf_lo(v3) +
            bf_lo(v4) + bf_lo(v5) + bf_lo(v6) + bf_lo(v7);
      a1 += bf_hi(v0) + bf_hi(v1) + bf_hi(v2) + bf_hi(v3) +
            bf_hi(v4) + bf_hi(v5) + bf_hi(v6) + bf_hi(v7);
    }
  }
  for (; j < len; j++) {
    int s = csr[start + j];
    if (act) {
      unsigned v = hp32[(size_t)s * 50 + lane];
      a0 += bf_lo(v); a1 += bf_hi(v);
    }
  }
  if (act) {
    float dv = dinv[node];
    float r0 = fmaxf(fmaf(dv, a0, b1[2 * lane]), 0.f);
    float r1 = fmaxf(fmaf(dv, a1, b1[2 * lane + 1]), 0.f);
    h1[(size_t)node * 50 + lane] = make_float2(r0, r1);
  }
}

// ---------- 6) p = dinv * (h1 @ W2) ----------
__global__ __launch_bounds__(256) void k_gemm2(const float* __restrict__ h1,
                                               const float* __restrict__ W2,
                                               const float* __restrict__ dinv,
                                               float* __restrict__ p) {
  __shared__ float xs[128 * 101];
  __shared__ float w2s[200];
  int t = threadIdx.x;
  int r0 = blockIdx.x * 128;
  if (t < 200) w2s[t] = W2[t];
  for (int idx = t; idx < 128 * 100; idx += 256) {
    int r = idx / 100, f = idx - r * 100;
    int g = r0 + r;
    xs[r * 101 + f] = (g < NN) ? h1[(size_t)g * 100 + f] : 0.f;
  }
  __syncthreads();
  int r = t >> 1, c = t & 1;
  int g = r0 + r;
  if (g < NN) {
    float acc = 0.f;
#pragma unroll
    for (int f = 0; f < 100; f++)
      acc = fmaf(xs[r * 101 + f], w2s[2 * f + c], acc);
    p[(size_t)g * 2 + c] = dinv[g] * acc;
  }
}

// ---------- 7) conv2 aggregate + skip + log_softmax ----------
// per-thread node; edge loop unrolled x4 (p table 800KB, mostly L2-resident)
__global__ __launch_bounds__(256) void k_final(const float2* __restrict__ p,
                                               const int* __restrict__ csr,
                                               const int* __restrict__ row_start,
                                               const int* __restrict__ cnt,
                                               const float* __restrict__ dinv,
                                               const float* __restrict__ b2,
                                               const float2* __restrict__ skip2,
                                               float2* __restrict__ out) {
  int i = blockIdx.x * 256 + threadIdx.x;
  if (i >= NN) return;
  float2 pi = p[i];
  float a0 = pi.x, a1 = pi.y;  // self-loop
  int start = row_start[i], len = cnt[i];
  int j = 0;
  for (; j + 4 <= len; j += 4) {
    int s0 = csr[start + j + 0], s1 = csr[start + j + 1];
    int s2 = csr[start + j + 2], s3 = csr[start + j + 3];
    float2 p0 = p[s0], p1 = p[s1], p2 = p[s2], p3 = p[s3];
    a0 += p0.x + p1.x + p2.x + p3.x;
    a1 += p0.y + p1.y + p2.y + p3.y;
  }
  for (; j < len; j++) {
    int s = csr[start + j];
    float2 ps = p[s];
    a0 += ps.x; a1 += ps.y;
  }
  float dv = dinv[i];
  float2 sk = skip2[i];
  float v0 = dv * a0 + b2[0] + sk.x;
  float v1 = dv * a1 + b2[1] + sk.y;
  float m = fmaxf(v0, v1);
  float lse = m + logf(expf(v0 - m) + expf(v1 - m));
  out[i] = make_float2(v0 - lse, v1 - lse);
}

extern "C" void kernel_launch(void* const* d_in, const int* in_sizes, int n_in,
                              void* d_out, int out_size, void* d_ws, size_t ws_size,
                              hipStream_t stream) {
  const float* x   = (const float*)d_in[0];
  const int*   ei  = (const int*)d_in[1];
  const float* W1  = (const float*)d_in[2];
  const float* b1  = (const float*)d_in[3];
  const float* W2  = (const float*)d_in[4];
  const float* b2  = (const float*)d_in[5];
  const float* Wsk = (const float*)d_in[6];
  const float* bsk = (const float*)d_in[7];
  float* out = (float*)d_out;

  char* w = (char*)d_ws;
  size_t off = 0;
  auto alloc = [&](size_t bytes) {
    void* ptr = w + off;
    off += (bytes + 255) & ~(size_t)255;
    return ptr;
  };
  int*      cnt   = (int*)alloc((size_t)NN * 4);
  int*      rs    = (int*)alloc((size_t)(NN + 1) * 4);
  int*      cur   = (int*)alloc((size_t)NN * 4);
  float*    dinv  = (float*)alloc((size_t)NN * 4);
  int*      csr   = (int*)alloc((size_t)EE * 4);
  unsigned* hp    = (unsigned*)alloc((size_t)NN * 50 * 4);  // bf16 x2 packed
  float*    skip2 = (float*)alloc((size_t)NN * 2 * 4);
  float*    h1    = (float*)alloc((size_t)NN * 100 * 4);
  float*    p     = (float*)alloc((size_t)NN * 2 * 4);
  short*    wt    = (short*)alloc((size_t)128 * 512 * 2);   // bf16 W^T padded
  int*      csum  = (int*)alloc((size_t)1024 * 4);
  int*      cbase = (int*)alloc((size_t)1024 * 4);

  hipMemsetAsync(cnt, 0, (size_t)NN * 4, stream);
  k_wprep<<<256, 256, 0, stream>>>(W1, Wsk, wt);
  k_hist<<<EE / 256, 256, 0, stream>>>(ei, cnt);
  k_chunksum<<<NCH, 128, 0, stream>>>(cnt, csum);
  k_scanchunks<<<1, 1024, 0, stream>>>(csum, cbase);
  k_emit<<<NCH, 128, 0, stream>>>(cnt, cbase, rs, cur, dinv);
  k_fill<<<(EE + 2047) / 2048, 256, 0, stream>>>(ei, cur, csr);
  k_gemm1m<<<(NN + 127) / 128, 256, 0, stream>>>(x, wt, bsk, dinv, hp, skip2);
  k_agg1<<<NN / 4, 256, 0, stream>>>(hp, csr, rs, cnt, dinv, b1, (float2*)h1);
  k_gemm2<<<(NN + 127) / 128, 256, 0, stream>>>(h1, W2, dinv, p);
  k_final<<<(NN + 255) / 256, 256, 0, stream>>>((const float2*)p, csr, rs, cnt,
                                                dinv, b2, (const float2*)skip2,
                                                (float2*)out);
}

// Round 16
// 503.735 us; speedup vs baseline: 4.9697x; 1.2585x over previous
//
#include <hip/hip_runtime.h>
#include <hip/hip_bf16.h>
#include <math.h>

#define NN 100000
#define EE 1600000
#define INC 512
#define HIDC 100
#define NB 391        // ceil(NN/256) buckets of 256 dst-nodes
#define PA_CHUNK 8192 // edges per partition block (512 thr x 16)
#define PA_GRID ((EE + PA_CHUNK - 1) / PA_CHUNK)  // 196

typedef __attribute__((ext_vector_type(8))) short bf16x8;
typedef __attribute__((ext_vector_type(4))) float f32x4;

static __device__ __forceinline__ unsigned short f2bf(float f) {
  unsigned u = __float_as_uint(f);
  return (unsigned short)((u + (0x7fffu + ((u >> 16) & 1u))) >> 16);
}
static __device__ __forceinline__ float bf_lo(unsigned v) {
  return __uint_as_float(v << 16);
}
static __device__ __forceinline__ float bf_hi(unsigned v) {
  return __uint_as_float(v & 0xffff0000u);
}

// swizzle for [row][64] bf16 tiles (128 B/row): XOR chunk bits with row&7
#define SWZ(row, byteoff) (((row) * 128 + ((byteoff) ^ (((row) & 7) << 4))))
// swizzle for [row][128] bf16 output tile (256 B/row)
#define SWZ2(row, byteoff) (((row) * 256 + ((byteoff) ^ (((row) & 7) << 4))))

// ---------- 0) W prep: wt[c][k] = bf16(W1[k][c] | Ws[k][c-100] | 0), c<128 ----------
__global__ void k_wprep(const float* __restrict__ W1, const float* __restrict__ Wsk,
                        short* __restrict__ wt) {
  int t = blockIdx.x * 256 + threadIdx.x;  // 65536 total
  int c = t >> 9, k = t & 511;
  float v = 0.f;
  if (c < 100) v = W1[k * 100 + c];
  else if (c < 102) v = Wsk[k * 2 + (c - 100)];
  wt[c * 512 + k] = (short)f2bf(v);
}

// ---------- 1a) coarse bucket histogram (LDS-staged) ----------
__global__ __launch_bounds__(512) void k_bcount(const int* __restrict__ ei,
                                                int* __restrict__ bcnt) {
  __shared__ int h[NB];
  for (int i = threadIdx.x; i < NB; i += 512) h[i] = 0;
  __syncthreads();
  int base = blockIdx.x * PA_CHUNK + threadIdx.x;
#pragma unroll
  for (int u = 0; u < 16; u++) {
    int e = base + u * 512;
    if (e < EE) atomicAdd(&h[ei[EE + e] >> 8], 1);
  }
  __syncthreads();
  for (int i = threadIdx.x; i < NB; i += 512)
    if (h[i]) atomicAdd(&bcnt[i], h[i]);
}

// ---------- 1b) scan bucket counts -> bucket bases + cursors ----------
__global__ __launch_bounds__(512) void k_bscan(const int* __restrict__ bcnt,
                                               int* __restrict__ bbase,
                                               int* __restrict__ bcur) {
  __shared__ int s[512];
  int t = threadIdx.x;
  s[t] = (t < NB) ? bcnt[t] : 0;
  __syncthreads();
  for (int off = 1; off < 512; off <<= 1) {
    int v = s[t];
    int u = (t >= off) ? s[t - off] : 0;
    __syncthreads();
    s[t] = v + u;
    __syncthreads();
  }
  if (t < NB) {
    int e = (t == 0) ? 0 : s[t - 1];
    bbase[t] = e;
    bcur[t] = e;
  }
}

// ---------- 1c) partition edges into bucket-ordered (dst,src) pairs ----------
__global__ __launch_bounds__(512) void k_passA(const int* __restrict__ ei,
                                               int* __restrict__ bcur,
                                               int2* __restrict__ ebuf) {
  __shared__ int h[NB], rb[NB], rk[NB];
  for (int i = threadIdx.x; i < NB; i += 512) { h[i] = 0; rk[i] = 0; }
  __syncthreads();
  int base = blockIdx.x * PA_CHUNK + threadIdx.x;
  int d[16], s[16];
#pragma unroll
  for (int u = 0; u < 16; u++) {
    int e = base + u * 512;
    d[u] = (e < EE) ? ei[EE + e] : -1;
    s[u] = (e < EE) ? ei[e] : 0;
    if (d[u] >= 0) atomicAdd(&h[d[u] >> 8], 1);
  }
  __syncthreads();
  for (int i = threadIdx.x; i < NB; i += 512)
    rb[i] = h[i] ? atomicAdd(&bcur[i], h[i]) : 0;
  __syncthreads();
#pragma unroll
  for (int u = 0; u < 16; u++) {
    if (d[u] >= 0) {
      int b = d[u] >> 8;
      int pos = rb[b] + atomicAdd(&rk[b], 1);
      ebuf[pos] = make_int2(d[u], s[u]);
    }
  }
}

// ---------- 1d) per-bucket: node counts, dinv, row_start, CSR fill ----------
__global__ __launch_bounds__(256) void k_bucket(const int2* __restrict__ ebuf,
                                                const int* __restrict__ bbase,
                                                const int* __restrict__ bcnt,
                                                int* __restrict__ cnt,
                                                int* __restrict__ row_start,
                                                float* __restrict__ dinv,
                                                int* __restrict__ csr) {
  __shared__ int c256[256], cur[256], s[256];
  int b = blockIdx.x, t = threadIdx.x;
  int eb = bbase[b], ec = bcnt[b];
  int node0 = b << 8;
  c256[t] = 0;
  __syncthreads();
  for (int i = t; i < ec; i += 256)
    atomicAdd(&c256[ebuf[eb + i].x - node0], 1);
  __syncthreads();
  int c = c256[t];
  s[t] = c;
  __syncthreads();
  for (int off = 1; off < 256; off <<= 1) {
    int v = s[t];
    int u = (t >= off) ? s[t - off] : 0;
    __syncthreads();
    s[t] = v + u;
    __syncthreads();
  }
  int excl = s[t] - c;
  int g = node0 + t;
  if (g < NN) {
    cnt[g] = c;
    dinv[g] = rsqrtf((float)(c + 1));  // +1 self-loop
    row_start[g] = eb + excl;
  }
  cur[t] = excl;
  __syncthreads();
  for (int i = t; i < ec; i += 256) {
    int2 e = ebuf[eb + i];
    int pos = atomicAdd(&cur[e.x - node0], 1);
    csr[eb + pos] = e.y;
  }
}

// ---------- 4) MFMA GEMM: hp = bf16(dinv*(x@W1)), skip2 = x@Ws + bs ----------
// tile: 128 rows x 128 cols (cols 0-99 = W1, 100-101 = Ws, 102-127 pad)
// K = 512, BK = 64, double-buffered LDS, bf16 mfma_f32_16x16x32
__global__ __launch_bounds__(256) void k_gemm1m(const float* __restrict__ x,
                                                const short* __restrict__ wt,
                                                const float* __restrict__ bsk,
                                                const float* __restrict__ dinv,
                                                unsigned* __restrict__ hp32,
                                                float* __restrict__ skip2) {
  __shared__ short xsb[2][8192];  // [128 rows][64 k] bf16 swizzled, 16 KB each
  __shared__ short wsb[2][8192];  // [128 cols][64 k] bf16 swizzled

  int t = threadIdx.x;
  int w = t >> 6, l = t & 63;
  int lane16 = l & 15, g = l >> 4;
  int row0 = blockIdx.x * 128;
  int r = t >> 1, h = t & 1;       // staging: thread -> (row/col r, k-half h)
  int grow_stage = row0 + r;

  f32x4 acc[2][8];
#pragma unroll
  for (int rt = 0; rt < 2; rt++)
#pragma unroll
    for (int ct = 0; ct < 8; ct++) acc[rt][ct] = (f32x4){0.f, 0.f, 0.f, 0.f};

  float xf[32];
  uint4 wv[4];

  // prologue: load slab 0 into regs
  {
    const float4* src = (const float4*)(x + (size_t)grow_stage * INC + h * 32);
#pragma unroll
    for (int i = 0; i < 8; i++) {
      float4 v = (grow_stage < NN) ? src[i] : (float4){0, 0, 0, 0};
      xf[i * 4 + 0] = v.x; xf[i * 4 + 1] = v.y; xf[i * 4 + 2] = v.z; xf[i * 4 + 3] = v.w;
    }
    const uint4* wsrc = (const uint4*)(wt + (size_t)r * 512 + h * 32);
#pragma unroll
    for (int j = 0; j < 4; j++) wv[j] = wsrc[j];
  }

  for (int s = 0; s < 8; s++) {
    int buf = s & 1;
    // write staged regs -> LDS (swizzled)
    {
      unsigned pk[16];
#pragma unroll
      for (int q = 0; q < 16; q++)
        pk[q] = (unsigned)f2bf(xf[2 * q]) | ((unsigned)f2bf(xf[2 * q + 1]) << 16);
#pragma unroll
      for (int j = 0; j < 4; j++)
        *(uint4*)((char*)&xsb[buf][0] + SWZ(r, h * 64 + j * 16)) = ((uint4*)pk)[j];
#pragma unroll
      for (int j = 0; j < 4; j++)
        *(uint4*)((char*)&wsb[buf][0] + SWZ(r, h * 64 + j * 16)) = wv[j];
    }
    __syncthreads();
    // issue next slab's global loads (hide under MFMA)
    if (s < 7) {
      int k0 = (s + 1) * 64;
      const float4* src = (const float4*)(x + (size_t)grow_stage * INC + k0 + h * 32);
#pragma unroll
      for (int i = 0; i < 8; i++) {
        float4 v = (grow_stage < NN) ? src[i] : (float4){0, 0, 0, 0};
        xf[i * 4 + 0] = v.x; xf[i * 4 + 1] = v.y; xf[i * 4 + 2] = v.z; xf[i * 4 + 3] = v.w;
      }
      const uint4* wsrc = (const uint4*)(wt + (size_t)r * 512 + k0 + h * 32);
#pragma unroll
      for (int j = 0; j < 4; j++) wv[j] = wsrc[j];
    }
    // compute slab
#pragma unroll
    for (int s2 = 0; s2 < 2; s2++) {
      bf16x8 a[2], b[8];
#pragma unroll
      for (int rt = 0; rt < 2; rt++)
        a[rt] = *(const bf16x8*)((char*)&xsb[buf][0] +
                                 SWZ(w * 32 + rt * 16 + lane16, s2 * 64 + g * 16));
#pragma unroll
      for (int ct = 0; ct < 8; ct++)
        b[ct] = *(const bf16x8*)((char*)&wsb[buf][0] +
                                 SWZ(ct * 16 + lane16, s2 * 64 + g * 16));
#pragma unroll
      for (int rt = 0; rt < 2; rt++)
#pragma unroll
        for (int ct = 0; ct < 8; ct++)
          acc[rt][ct] = __builtin_amdgcn_mfma_f32_16x16x32_bf16(a[rt], b[ct], acc[rt][ct], 0, 0, 0);
    }
    __syncthreads();
  }

  // epilogue: acc -> LDS (bf16, swizzled 256B rows), then coalesced readback
  short* ob = (short*)&xsb[0][0];  // 32 KB = 128 rows x 128 cols bf16
#pragma unroll
  for (int rt = 0; rt < 2; rt++)
#pragma unroll
    for (int ct = 0; ct < 8; ct++)
#pragma unroll
      for (int i = 0; i < 4; i++) {
        int rloc = w * 32 + rt * 16 + g * 4 + i;
        int col = ct * 16 + lane16;
        *(short*)((char*)ob + SWZ2(rloc, col * 2)) = (short)f2bf(acc[rt][ct][i]);
      }
  __syncthreads();

  int grow = row0 + r;
  if (grow < NN) {
    float dv = dinv[grow];
    unsigned v[32];
#pragma unroll
    for (int j = 0; j < 8; j++)
      ((uint4*)v)[j] = *(const uint4*)((char*)ob + SWZ2(r, h * 128 + j * 16));
    if (h == 0) {
      // cols 0..63 -> hp words 0..31
#pragma unroll
      for (int q = 0; q < 32; q++) {
        unsigned o = (unsigned)f2bf(dv * bf_lo(v[q])) |
                     ((unsigned)f2bf(dv * bf_hi(v[q])) << 16);
        hp32[(size_t)grow * 50 + q] = o;
      }
    } else {
      // cols 64..99 -> hp words 32..49; cols 100,101 -> skip2
#pragma unroll
      for (int q = 0; q < 18; q++) {
        unsigned o = (unsigned)f2bf(dv * bf_lo(v[q])) |
                     ((unsigned)f2bf(dv * bf_hi(v[q])) << 16);
        hp32[(size_t)grow * 50 + 32 + q] = o;
      }
      skip2[(size_t)grow * 2 + 0] = bf_lo(v[18]) + bsk[0];
      skip2[(size_t)grow * 2 + 1] = bf_hi(v[18]) + bsk[1];
    }
  }
}

// ---------- 5) aggregate conv1: h1 = relu(dinv*(sum hp[src] + hp[i]) + b1) ----------
// one wave per node; edge loop unrolled x8 -> 8 independent 200B gathers in flight
__global__ __launch_bounds__(256) void k_agg1(const unsigned* __restrict__ hp32,
                                              const int* __restrict__ csr,
                                              const int* __restrict__ row_start,
                                              const int* __restrict__ cnt,
                                              const float* __restrict__ dinv,
                                              const float* __restrict__ b1,
                                              float2* __restrict__ h1) {
  int node = blockIdx.x * 4 + (threadIdx.x >> 6);  // one wave per node
  int lane = threadIdx.x & 63;
  bool act = lane < 50;
  int start = row_start[node];
  int len = cnt[node];
  float a0 = 0.f, a1 = 0.f;
  if (act) {
    unsigned v = hp32[(size_t)node * 50 + lane];  // self-loop term
    a0 = bf_lo(v); a1 = bf_hi(v);
  }
  int j = 0;
  for (; j + 8 <= len; j += 8) {
    int s0 = csr[start + j + 0], s1 = csr[start + j + 1];
    int s2 = csr[start + j + 2], s3 = csr[start + j + 3];
    int s4 = csr[start + j + 4], s5 = csr[start + j + 5];
    int s6 = csr[start + j + 6], s7 = csr[start + j + 7];
    if (act) {
      unsigned v0 = hp32[(size_t)s0 * 50 + lane];
      unsigned v1 = hp32[(size_t)s1 * 50 + lane];
      unsigned v2 = hp32[(size_t)s2 * 50 + lane];
      unsigned v3 = hp32[(size_t)s3 * 50 + lane];
      unsigned v4 = hp32[(size_t)s4 * 50 + lane];
      unsigned v5 = hp32[(size_t)s5 * 50 + lane];
      unsigned v6 = hp32[(size_t)s6 * 50 + lane];
      unsigned v7 = hp32[(size_t)s7 * 50 + lane];
      a0 += bf_lo(v0) + bf_lo(v1) + bf_lo(v2) + bf_lo(v3) +
            bf_lo(v4) + bf_lo(v5) + bf_lo(v6) + bf_lo(v7);
      a1 += bf_hi(v0) + bf_hi(v1) + bf_hi(v2) + bf_hi(v3) +
            bf_hi(v4) + bf_hi(v5) + bf_hi(v6) + bf_hi(v7);
    }
  }
  for (; j < len; j++) {
    int s = csr[start + j];
    if (act) {
      unsigned v = hp32[(size_t)s * 50 + lane];
      a0 += bf_lo(v); a1 += bf_hi(v);
    }
  }
  if (act) {
    float dv = dinv[node];
    float r0 = fmaxf(fmaf(dv, a0, b1[2 * lane]), 0.f);
    float r1 = fmaxf(fmaf(dv, a1, b1[2 * lane + 1]), 0.f);
    h1[(size_t)node * 50 + lane] = make_float2(r0, r1);
  }
}

// ---------- 6) p = dinv * (h1 @ W2) ----------
__global__ __launch_bounds__(256) void k_gemm2(const float* __restrict__ h1,
                                               const float* __restrict__ W2,
                                               const float* __restrict__ dinv,
                                               float* __restrict__ p) {
  __shared__ float xs[128 * 101];
  __shared__ float w2s[200];
  int t = threadIdx.x;
  int r0 = blockIdx.x * 128;
  if (t < 200) w2s[t] = W2[t];
  for (int idx = t; idx < 128 * 100; idx += 256) {
    int r = idx / 100, f = idx - r * 100;
    int g = r0 + r;
    xs[r * 101 + f] = (g < NN) ? h1[(size_t)g * 100 + f] : 0.f;
  }
  __syncthreads();
  int r = t >> 1, c = t & 1;
  int g = r0 + r;
  if (g < NN) {
    float acc = 0.f;
#pragma unroll
    for (int f = 0; f < 100; f++)
      acc = fmaf(xs[r * 101 + f], w2s[2 * f + c], acc);
    p[(size_t)g * 2 + c] = dinv[g] * acc;
  }
}

// ---------- 7) conv2 aggregate + skip + log_softmax ----------
// per-thread node; edge loop unrolled x4 (p table 800KB, mostly L2-resident)
__global__ __launch_bounds__(256) void k_final(const float2* __restrict__ p,
                                               const int* __restrict__ csr,
                                               const int* __restrict__ row_start,
                                               const int* __restrict__ cnt,
                                               const float* __restrict__ dinv,
                                               const float* __restrict__ b2,
                                               const float2* __restrict__ skip2,
                                               float2* __restrict__ out) {
  int i = blockIdx.x * 256 + threadIdx.x;
  if (i >= NN) return;
  float2 pi = p[i];
  float a0 = pi.x, a1 = pi.y;  // self-loop
  int start = row_start[i], len = cnt[i];
  int j = 0;
  for (; j + 4 <= len; j += 4) {
    int s0 = csr[start + j + 0], s1 = csr[start + j + 1];
    int s2 = csr[start + j + 2], s3 = csr[start + j + 3];
    float2 p0 = p[s0], p1 = p[s1], p2 = p[s2], p3 = p[s3];
    a0 += p0.x + p1.x + p2.x + p3.x;
    a1 += p0.y + p1.y + p2.y + p3.y;
  }
  for (; j < len; j++) {
    int s = csr[start + j];
    float2 ps = p[s];
    a0 += ps.x; a1 += ps.y;
  }
  float dv = dinv[i];
  float2 sk = skip2[i];
  float v0 = dv * a0 + b2[0] + sk.x;
  float v1 = dv * a1 + b2[1] + sk.y;
  float m = fmaxf(v0, v1);
  float lse = m + logf(expf(v0 - m) + expf(v1 - m));
  out[i] = make_float2(v0 - lse, v1 - lse);
}

extern "C" void kernel_launch(void* const* d_in, const int* in_sizes, int n_in,
                              void* d_out, int out_size, void* d_ws, size_t ws_size,
                              hipStream_t stream) {
  const float* x   = (const float*)d_in[0];
  const int*   ei  = (const int*)d_in[1];
  const float* W1  = (const float*)d_in[2];
  const float* b1  = (const float*)d_in[3];
  const float* W2  = (const float*)d_in[4];
  const float* b2  = (const float*)d_in[5];
  const float* Wsk = (const float*)d_in[6];
  const float* bsk = (const float*)d_in[7];
  float* out = (float*)d_out;

  char* w = (char*)d_ws;
  size_t off = 0;
  auto alloc = [&](size_t bytes) {
    void* ptr = w + off;
    off += (bytes + 255) & ~(size_t)255;
    return ptr;
  };
  int*      cnt   = (int*)alloc((size_t)NN * 4);
  int*      rs    = (int*)alloc((size_t)NN * 4);
  float*    dinv  = (float*)alloc((size_t)NN * 4);
  int*      csr   = (int*)alloc((size_t)EE * 4);
  unsigned* hp    = (unsigned*)alloc((size_t)NN * 50 * 4);  // bf16 x2 packed
  float*    skip2 = (float*)alloc((size_t)NN * 2 * 4);
  float*    h1    = (float*)alloc((size_t)NN * 100 * 4);
  float*    p     = (float*)alloc((size_t)NN * 2 * 4);
  short*    wt    = (short*)alloc((size_t)128 * 512 * 2);   // bf16 W^T padded
  int*      bcnt  = (int*)alloc((size_t)512 * 4);
  int*      bbase = (int*)alloc((size_t)512 * 4);
  int*      bcur  = (int*)alloc((size_t)512 * 4);
  int2*     ebuf  = (int2*)h1;  // 12.8MB staging aliases h1 (40MB, disjoint lifetime)

  hipMemsetAsync(bcnt, 0, (size_t)512 * 4, stream);
  k_wprep<<<256, 256, 0, stream>>>(W1, Wsk, wt);
  k_bcount<<<PA_GRID, 512, 0, stream>>>(ei, bcnt);
  k_bscan<<<1, 512, 0, stream>>>(bcnt, bbase, bcur);
  k_passA<<<PA_GRID, 512, 0, stream>>>(ei, bcur, ebuf);
  k_bucket<<<NB, 256, 0, stream>>>(ebuf, bbase, bcnt, cnt, rs, dinv, csr);
  k_gemm1m<<<(NN + 127) / 128, 256, 0, stream>>>(x, wt, bsk, dinv, hp, skip2);
  k_agg1<<<NN / 4, 256, 0, stream>>>(hp, csr, rs, cnt, dinv, b1, (float2*)h1);
  k_gemm2<<<(NN + 127) / 128, 256, 0, stream>>>(h1, W2, dinv, p);
  k_final<<<(NN + 255) / 256, 256, 0, stream>>>((const float2*)p, csr, rs, cnt,
                                                dinv, b2, (const float2*)skip2,
                                                (float2*)out);
}